// Round 2
// baseline (486.070 us; speedup 1.0000x reference)
//
#include <hip/hip_runtime.h>

typedef unsigned int u32;
typedef _Float16 f16;
typedef f16 h2 __attribute__((ext_vector_type(2)));

// ---------------- packed-weight ws layout (u32/f32 element offsets) ----------
#define QP     0        // [e<32][i<8] half2 pairs over f           (256)
#define KVP    256      // [e<64][i<8]                              (512)
#define WOP    768      // [f<16][i<16] pairs over e                (256)
#define ILWP   1024     // [(jp4<64 *32 + t)*4 + i] pairs over j    (8192)
#define WIHP   9216     // [(kp<16 *32 + t)*4 + j] j<3 used         (2048)
#define WHHP   11264    //                                          (2048)
#define MSWP   13312    // [kp<16 *32 + t]                          (512)
#define MGWP   13824    // [a*512 + kp<16 *32 + m]                  (32768)
#define QSWP   46592    // [kp<32 *32 + t]                          (1024)
#define AHWP   47616    // [a*256 + kp<16 *16 + u]                  (16384)
#define F32B   64000
#define BQ     (F32B+0)     // 32
#define BKV    (F32B+32)    // 64
#define BO     (F32B+96)    // 16
#define LN1G   (F32B+112)   // 16
#define LN1B   (F32B+128)   // 16
#define ILB    (F32B+144)   // 32
#define BIH    (F32B+176)   // 96
#define BHH    (F32B+272)   // 96
#define MSB    (F32B+368)   // 32
#define MGB    (F32B+400)   // 2048
#define MAWKVV (F32B+2448)  // 1024  wkv_V as [k<32][t<32]
#define MABKVV (F32B+3472)  // 32
#define MAWO   (F32B+3504)  // 1024
#define MABO   (F32B+4528)  // 32
#define LN2G   (F32B+4560)  // 32
#define LN2B   (F32B+4592)  // 32
#define QSB    (F32B+4624)  // 32
#define AHB    (F32B+4656)  // 1024
#define W_TOTAL (F32B+5680)
#define W_ALLOC 69696

// output element offsets (f32): q_values | h | mean_message
#define OUT_Q  0
#define OUT_H  1048576
#define OUT_MM 3145728

// softmax scale folded into wq/bq at repack time, in exp2 domain:
// CS = (1/sqrt(8)) * log2(e); score' = CS*(Q.K)  =>  exp(score*scale) = 2^score'
#define CS (0.35355339059327373f * 1.4426950408889634f)

// zero-cost compiler code-motion fence: guards type-punned LDS overlays
// (hardware same-wave DS ordering is already in-order; this only stops
// clang TBAA from reordering float vs uint4/float4 accesses to aliases)
#if __has_builtin(__builtin_amdgcn_wave_barrier)
#define WB() __builtin_amdgcn_wave_barrier()
#else
#define WB() __threadfence_block()
#endif

#if __has_builtin(__builtin_amdgcn_exp2f)
__device__ __forceinline__ float EXP2(float x) { return __builtin_amdgcn_exp2f(x); }
#else
__device__ __forceinline__ float EXP2(float x) { return __expf(x * 0.6931471805599453f); }
#endif

#if __has_builtin(__builtin_amdgcn_fdot2)
__device__ __forceinline__ float FD(h2 a, h2 b, float c) {
    return __builtin_amdgcn_fdot2(a, b, c, false);
}
#else
__device__ __forceinline__ float FD(h2 a, h2 b, float c) {
    return c + (float)a.x * (float)b.x + (float)a.y * (float)b.y;
}
#endif

#if __has_builtin(__builtin_amdgcn_cvt_pkrtz)
__device__ __forceinline__ h2 pk2(float a, float b) {
    auto r = __builtin_amdgcn_cvt_pkrtz(a, b);   // __fp16 vec2 on this clang
    h2 out;
    __builtin_memcpy(&out, &r, sizeof(out));      // no-op bitcast
    return out;
}
#else
__device__ __forceinline__ h2 pk2(float a, float b) { h2 r; r.x = (f16)a; r.y = (f16)b; return r; }
#endif

__device__ __forceinline__ h2  u2h(u32 x) { union { u32 u; h2 h; } c; c.u = x; return c.h; }
__device__ __forceinline__ u32 h2u(h2 x)  { union { u32 u; h2 h; } c; c.h = x; return c.u; }

__device__ __forceinline__ float sigm(float x) { return 1.0f / (1.0f + __expf(-x)); }

struct WP { const float* p[30]; };

// K0: repack weights: f16 pairs (packed along contraction dim) + f32 tail
__global__ void kw_conv(WP wp, float* W) {
    u32* Wu = (u32*)W;
    int gid = blockIdx.x * blockDim.x + threadIdx.x;
    if (gid >= W_TOTAL) return;
    if (gid < KVP) {                       // QP: ia_wq [16][32]  (x CS fold)
        int e = gid >> 3, i = gid & 7;
        const float* wq = wp.p[0];
        Wu[gid] = h2u(pk2(wq[(2*i)*32 + e] * CS, wq[(2*i+1)*32 + e] * CS));
    } else if (gid < WOP) {                // KVP: ia_wkv [16][64]
        int idx = gid - KVP; int e = idx >> 3, i = idx & 7;
        const float* wkv = wp.p[2];
        Wu[gid] = h2u(pk2(wkv[(2*i)*64 + e], wkv[(2*i+1)*64 + e]));
    } else if (gid < ILWP) {               // WOP: ia_wo [32][16]
        int idx = gid - WOP; int f = idx >> 4, i = idx & 15;
        const float* wo = wp.p[4];
        Wu[gid] = h2u(pk2(wo[(2*i)*16 + f], wo[(2*i+1)*16 + f]));
    } else if (gid < WIHP) {               // ILWP: il_w [512][32]
        int idx = gid - ILWP;
        int jp4 = idx >> 7, t = (idx >> 2) & 31, i = idx & 3;
        int jp = jp4 * 4 + i;
        const float* ilw = wp.p[8];
        Wu[gid] = h2u(pk2(ilw[(2*jp)*32 + t], ilw[(2*jp+1)*32 + t]));
    } else if (gid < WHHP) {               // WIHP: gru_wih [32][96]
        int idx = gid - WIHP;
        int kp = idx >> 7, t = (idx >> 2) & 31, j = idx & 3;
        const float* wih = wp.p[10];
        Wu[gid] = (j < 3) ? h2u(pk2(wih[(2*kp)*96 + j*32 + t], wih[(2*kp+1)*96 + j*32 + t])) : 0u;
    } else if (gid < MSWP) {               // WHHP: gru_whh [32][96]
        int idx = gid - WHHP;
        int kp = idx >> 7, t = (idx >> 2) & 31, j = idx & 3;
        const float* whh = wp.p[11];
        Wu[gid] = (j < 3) ? h2u(pk2(whh[(2*kp)*96 + j*32 + t], whh[(2*kp+1)*96 + j*32 + t])) : 0u;
    } else if (gid < MGWP) {               // MSWP: ms_w [32][32]
        int idx = gid - MSWP; int kp = idx >> 5, t = idx & 31;
        const float* msw = wp.p[14];
        Wu[gid] = h2u(pk2(msw[(2*kp)*32 + t], msw[(2*kp+1)*32 + t]));
    } else if (gid < QSWP) {               // MGWP: mg_w [64][32][32]
        int idx = gid - MGWP; int a = idx >> 9, rem = idx & 511, kp = rem >> 5, m = rem & 31;
        const float* mgw = wp.p[16];
        Wu[gid] = h2u(pk2(mgw[(a*32 + 2*kp)*32 + m], mgw[(a*32 + 2*kp+1)*32 + m]));
    } else if (gid < AHWP) {               // QSWP: qs_w [64][32]
        int idx = gid - QSWP; int kp = idx >> 5, t = idx & 31;
        const float* qsw = wp.p[26];
        Wu[gid] = h2u(pk2(qsw[(2*kp)*32 + t], qsw[(2*kp+1)*32 + t]));
    } else if (gid < F32B) {               // AHWP: ah_w [64][32][16]
        int idx = gid - AHWP; int a = idx >> 8, rem = idx & 255, kp = rem >> 4, u = rem & 15;
        const float* ahw = wp.p[28];
        Wu[gid] = h2u(pk2(ahw[(a*32 + 2*kp)*16 + u], ahw[(a*32 + 2*kp+1)*16 + u]));
    } else {                               // f32 tail
        int i = gid - F32B;
        float v;
        if      (i < 32)   v = wp.p[1][i] * CS;            // bq (x CS fold)
        else if (i < 96)   v = wp.p[3][i - 32];            // bkv
        else if (i < 112)  v = wp.p[5][i - 96];            // bo
        else if (i < 128)  v = wp.p[6][i - 112];           // ln1_g
        else if (i < 144)  v = wp.p[7][i - 128];           // ln1_b
        else if (i < 176)  v = wp.p[9][i - 144];           // il_b
        else if (i < 272)  v = wp.p[12][i - 176];          // gru_bih
        else if (i < 368)  v = wp.p[13][i - 272];          // gru_bhh
        else if (i < 400)  v = wp.p[15][i - 368];          // ms_b
        else if (i < 2448) v = wp.p[17][i - 400];          // mg_b
        else if (i < 3472) { int j = i - 2448; v = wp.p[20][(j >> 5)*64 + 32 + (j & 31)]; } // ma_wkv V
        else if (i < 3504) v = wp.p[21][32 + (i - 3472)];  // ma_bkv V
        else if (i < 4528) v = wp.p[22][i - 3504];         // ma_wo
        else if (i < 4560) v = wp.p[23][i - 4528];         // ma_bo
        else if (i < 4592) v = wp.p[24][i - 4560];         // ln2_g
        else if (i < 4624) v = wp.p[25][i - 4592];         // ln2_b
        else if (i < 4656) v = wp.p[27][i - 4624];         // qs_b
        else               v = wp.p[29][i - 4656];         // ah_b
        W[gid] = v;
    }
}

// K1: per wave = 2 agents. lane = (sub<<5)|t ; t = link/row index.
// ALL LDS regions are wave-private ([ag] with ag owned by the wave), so no
// __syncthreads is needed anywhere: same-wave DS ops execute in order at the
// hardware level; WB() (zero-instruction wave_barrier) pins the compiler's
// memory-op order at every type-punned overlay transition.
// LDS exactly 32 KiB -> 5 blocks/CU (20 waves). Scratch (enc/hn/memb)
// overlays VbH[ag] (dead after P2); h is re-read from global (L1-warm).
__global__ __launch_bounds__(256, 5) void k_main(
    const float* __restrict__ states, const float* __restrict__ hidden,
    const float* W, float* __restrict__ outp)
{
    const u32* Wu = (const u32*)W;

    __shared__ uint4 KbH[8][32][4];   // f16 K rows (swizzled); later: aft rows
    __shared__ uint4 VbH[8][32][4];   // f16 V rows (swizzled); later: scratch

    const int w    = threadIdx.x >> 6;
    const int lane = threadIdx.x & 63;
    const int sub  = lane >> 5;
    const int t    = lane & 31;
    const int ag   = w * 2 + sub;
    const int pair = blockIdx.x * 4 + w;
    const int b    = pair >> 5;
    const int a    = ((pair & 31) << 1) | sub;
    const int ba   = b * 64 + a;

    float* scr = (float*)&VbH[ag][0][0];   // 512 f32; [0..31]=enc [64..95]=hn [96..127]=memb

    // ---- P0: states row (link t): 16 f32; hidden value (latency overlap) ----
    float s[16];
    {
        const float4* p4 = reinterpret_cast<const float4*>(states + ((size_t)ba * 32 + t) * 16);
        float4 f0 = p4[0], f1 = p4[1], f2 = p4[2], f3 = p4[3];
        s[0]=f0.x; s[1]=f0.y; s[2]=f0.z; s[3]=f0.w;
        s[4]=f1.x; s[5]=f1.y; s[6]=f1.z; s[7]=f1.w;
        s[8]=f2.x; s[9]=f2.y; s[10]=f2.z; s[11]=f2.w;
        s[12]=f3.x; s[13]=f3.y; s[14]=f3.z; s[15]=f3.w;
    }
    float hp = hidden[(size_t)ba * 32 + t];
    h2 sh[8];
    #pragma unroll
    for (int i = 0; i < 8; ++i) sh[i] = pk2(s[2*i], s[2*i+1]);

    // ---- P1a: Q (packed pairs; weights wave-uniform -> s_load). wq/bq carry
    //           the CS = scale*log2e fold, so scores land in exp2 domain. ----
    h2 qh[16];
    #pragma unroll
    for (int j = 0; j < 16; ++j) {
        float a0 = W[BQ + 2*j], a1 = W[BQ + 2*j + 1];
        #pragma unroll
        for (int i = 0; i < 8; ++i) {
            a0 = FD(sh[i], u2h(Wu[QP + (2*j)*8 + i]), a0);
            a1 = FD(sh[i], u2h(Wu[QP + (2*j+1)*8 + i]), a1);
        }
        qh[j] = pk2(a0, a1);
    }
    // ---- P1b: K,V rows -> f16 LDS (swizzled cols) ----
    #pragma unroll
    for (int u = 0; u < 4; ++u) {
        u32 kc[4], vc[4];
        #pragma unroll
        for (int c = 0; c < 4; ++c) {
            int e0 = u*8 + 2*c, e1 = e0 + 1;
            float k0 = W[BKV+e0], k1 = W[BKV+e1];
            float v0 = W[BKV+32+e0], v1 = W[BKV+32+e1];
            #pragma unroll
            for (int i = 0; i < 8; ++i) {
                k0 = FD(sh[i], u2h(Wu[KVP + e0*8 + i]), k0);
                k1 = FD(sh[i], u2h(Wu[KVP + e1*8 + i]), k1);
                v0 = FD(sh[i], u2h(Wu[KVP + (32+e0)*8 + i]), v0);
                v1 = FD(sh[i], u2h(Wu[KVP + (32+e1)*8 + i]), v1);
            }
            kc[c] = h2u(pk2(k0, k1)); vc[c] = h2u(pk2(v0, v1));
        }
        int uc = u ^ (t & 3);
        KbH[ag][t][uc] = make_uint4(kc[0], kc[1], kc[2], kc[3]);
        VbH[ag][t][uc] = make_uint4(vc[0], vc[1], vc[2], vc[3]);
    }
    WB();   // K/V writes ordered before P2 reads (same wave, in-order DS pipe)

    // ---- P2: 4-head attention; fused score+PV loop (no scf array);
    //          e = exp2(sc) (scale pre-folded); PV in packed f16 ----
    h2 oh[16];
    #pragma unroll
    for (int hh = 0; hh < 4; ++hh) {
        float l = 0.0f;
        h2 ov0 = {(f16)0, (f16)0}, ov1 = ov0, ov2 = ov0, ov3 = ov0;
        #pragma unroll
        for (int k = 0; k < 32; ++k) {
            uint4 kr = KbH[ag][k][hh ^ (k & 3)];   // uniform addr -> broadcast
            float sc = 0.0f;
            sc = FD(qh[hh*4+0], u2h(kr.x), sc);
            sc = FD(qh[hh*4+1], u2h(kr.y), sc);
            sc = FD(qh[hh*4+2], u2h(kr.z), sc);
            sc = FD(qh[hh*4+3], u2h(kr.w), sc);
            float e = EXP2(sc);
            l += e;
            h2 ph = pk2(e, e);
            uint4 vr = VbH[ag][k][hh ^ (k & 3)];
            ov0 += ph * u2h(vr.x);
            ov1 += ph * u2h(vr.y);
            ov2 += ph * u2h(vr.z);
            ov3 += ph * u2h(vr.w);
        }
        float inv = 1.0f / l;
        h2 hinv = pk2(inv, inv);
        oh[hh*4+0] = ov0 * hinv; oh[hh*4+1] = ov1 * hinv;
        oh[hh*4+2] = ov2 * hinv; oh[hh*4+3] = ov3 * hinv;
    }
    WB();   // all KbH/VbH reads complete-in-order before overlay writes below

    // ---- P3: out proj + residual + LayerNorm(16) ----
    float aft[16];
    {
        float x[16];
        float mean = 0.0f;
        #pragma unroll
        for (int f = 0; f < 16; ++f) {
            float acc = W[BO + f];
            #pragma unroll
            for (int i = 0; i < 16; ++i) acc = FD(oh[i], u2h(Wu[WOP + f*16 + i]), acc);
            x[f] = s[f] + acc;
            mean += x[f];
        }
        mean *= (1.0f / 16.0f);
        float var = 0.0f;
        #pragma unroll
        for (int f = 0; f < 16; ++f) { float d = x[f] - mean; var += d * d; }
        var *= (1.0f / 16.0f);
        float rs = rsqrtf(var + 1e-5f);
        #pragma unroll
        for (int f = 0; f < 16; ++f)
            aft[f] = (x[f] - mean) * rs * W[LN1G + f] + W[LN1B + f];
    }
    // aft rows -> LDS, overlaying KbH[ag] (dead after P2; ordered by WB above)
    uint4* aftA = &KbH[ag][0][0];   // 64 uint4 per ag-group
    {
        u32 ac[8];
        #pragma unroll
        for (int c = 0; c < 8; ++c) ac[c] = h2u(pk2(aft[2*c], aft[2*c+1]));
        aftA[2*t]     = make_uint4(ac[0], ac[1], ac[2], ac[3]);
        aftA[2*t + 1] = make_uint4(ac[4], ac[5], ac[6], ac[7]);
    }
    WB();   // aft writes ordered before P4 reads

    // ---- P4: enc[t] = il_b[t] + aft_flat . il_w[:,t]  (f16 dot2) ----
    float enc = W[ILB + t];
    {
        const uint4* aA   = aftA;
        const uint4* ilw4 = (const uint4*)(Wu + ILWP);
        #pragma unroll 8
        for (int jp4 = 0; jp4 < 64; ++jp4) {
            uint4 av = aA[jp4];
            uint4 wv = ilw4[jp4 * 32 + t];
            enc = FD(u2h(av.x), u2h(wv.x), enc);
            enc = FD(u2h(av.y), u2h(wv.y), enc);
            enc = FD(u2h(av.z), u2h(wv.z), enc);
            enc = FD(u2h(av.w), u2h(wv.w), enc);
        }
    }
    WB();
    scr[t] = enc;   // overlays VbH[ag] (dead after P2; WB-fenced)
    WB();

    // ---- P5: GRU (h row re-read from global: uniform f4 broadcast, L1-warm) ----
    float gi0 = W[BIH + t], gi1 = W[BIH + 32 + t], gi2 = W[BIH + 64 + t];
    float gh0 = W[BHH + t], gh1 = W[BHH + 32 + t], gh2 = W[BHH + 64 + t];
    {
        const float4* eF = (const float4*)scr;
        const float4* hF = (const float4*)(hidden + (size_t)ba * 32);
        const uint4* wi4 = (const uint4*)(Wu + WIHP);
        const uint4* wh4 = (const uint4*)(Wu + WHHP);
        #pragma unroll
        for (int q4 = 0; q4 < 8; ++q4) {
            float4 ev = eF[q4], hv = hF[q4];
            h2 ea = pk2(ev.x, ev.y), eb = pk2(ev.z, ev.w);
            h2 ha = pk2(hv.x, hv.y), hb = pk2(hv.z, hv.w);
            uint4 wiA = wi4[(q4*2)*32 + t], wiB = wi4[(q4*2+1)*32 + t];
            uint4 whA = wh4[(q4*2)*32 + t], whB = wh4[(q4*2+1)*32 + t];
            gi0 = FD(ea, u2h(wiA.x), gi0); gi1 = FD(ea, u2h(wiA.y), gi1); gi2 = FD(ea, u2h(wiA.z), gi2);
            gi0 = FD(eb, u2h(wiB.x), gi0); gi1 = FD(eb, u2h(wiB.y), gi1); gi2 = FD(eb, u2h(wiB.z), gi2);
            gh0 = FD(ha, u2h(whA.x), gh0); gh1 = FD(ha, u2h(whA.y), gh1); gh2 = FD(ha, u2h(whA.z), gh2);
            gh0 = FD(hb, u2h(whB.x), gh0); gh1 = FD(hb, u2h(whB.y), gh1); gh2 = FD(hb, u2h(whB.z), gh2);
        }
    }
    float r  = sigm(gi0 + gh0);
    float z  = sigm(gi1 + gh1);
    float n  = tanhf(gi2 + r * gh2);
    float hn = (1.0f - z) * n + z * hp;
    outp[OUT_H + (size_t)ba * 32 + t] = hn;
    WB();
    scr[64 + t] = hn;
    WB();

    // ---- P6: memb = relu(h @ ms_w + b); msg = memb @ mg_w[a] + b ----
    {
        const float4* nF = (const float4*)(scr + 64);
        float mb = W[MSB + t];
        #pragma unroll
        for (int q4 = 0; q4 < 8; ++q4) {
            float4 v = nF[q4];
            h2 a2 = pk2(v.x, v.y), b2 = pk2(v.z, v.w);
            mb = FD(a2, u2h(Wu[MSWP + (q4*2)*32 + t]), mb);
            mb = FD(b2, u2h(Wu[MSWP + (q4*2+1)*32 + t]), mb);
        }
        mb = fmaxf(mb, 0.0f);
        WB();
        scr[96 + t] = mb;
        WB();
    }
    {
        const float4* mF = (const float4*)(scr + 96);
        float mg = W[MGB + a * 32 + t];
        #pragma unroll
        for (int q4 = 0; q4 < 8; ++q4) {
            float4 v = mF[q4];
            h2 a2 = pk2(v.x, v.y), b2 = pk2(v.z, v.w);
            mg = FD(a2, u2h(Wu[MGWP + a*512 + (q4*2)*32 + t]), mg);
            mg = FD(b2, u2h(Wu[MGWP + a*512 + (q4*2+1)*32 + t]), mg);
        }
        // stash raw per-agent message; k_tail2 overwrites with the mean
        outp[OUT_MM + (size_t)ba * 32 + t] = mg;
    }
}

// K2 (fused k_mean+k_tail): one block per batch item b.
// Phase 1: mean over 64 agents (in-place over OUT_MM) + degenerate comm-attn
//   (sl=1 => softmax==1 => ao = (mm @ wkv_V + bkv_V) @ wo + bo, per batch),
//   both 32x32 matvecs 8-way parallelized across half-waves.
// Phase 2: 8 iterations; each half-wave c handles agent a = it*8+c:
//   LN2(h+ao) -> feat=[h,after] -> relu(qs) -> per-agent Q head.
//   featS/qeS are half-wave-private -> WB() fences instead of barriers.
__global__ __launch_bounds__(256) void k_tail2(const float* W, float* __restrict__ outp)
{
    const u32* Wu = (const u32*)W;
    const int b   = blockIdx.x;
    const int tid = threadIdx.x;
    const int t   = tid & 31;
    const int c   = tid >> 5;        // 0..7
    __shared__ float pS[8][32];
    __shared__ float mmS[32];
    __shared__ float vS[32];
    __shared__ float aoS[32];
    __shared__ __align__(16) float featS[8][64];
    __shared__ __align__(16) float qeS[8][32];

    // mean over 64 agents (8-way partials)
    float acc = 0.0f;
    #pragma unroll
    for (int a2 = 0; a2 < 8; ++a2)
        acc += outp[OUT_MM + ((size_t)b * 64 + (a2 * 8 + c)) * 32 + t];
    pS[c][t] = acc;
    __syncthreads();
    if (tid < 32) {
        float ssum = 0.0f;
        #pragma unroll
        for (int cc = 0; cc < 8; ++cc) ssum += pS[cc][t];
        mmS[t] = ssum * (1.0f / 64.0f);
    }
    __syncthreads();
    // write mean_message output (broadcast to all 64 agents)
    {
        float mv = mmS[t];
        for (int i = tid; i < 2048; i += 256)
            outp[OUT_MM + (size_t)b * 2048 + i] = mv;   // i & 31 == t
    }
    // v = mm @ wkv_V + bkv_V  (each half-wave covers 4 k's)
    {
        float pv = 0.0f;
        #pragma unroll
        for (int kk = 0; kk < 4; ++kk) {
            int k = c * 4 + kk;
            pv += mmS[k] * W[MAWKVV + k * 32 + t];
        }
        pS[c][t] = pv;   // safe: prior pS readers finished before last barrier
    }
    __syncthreads();
    if (tid < 32) {
        float v = W[MABKVV + t];
        #pragma unroll
        for (int cc = 0; cc < 8; ++cc) v += pS[cc][t];
        vS[t] = v;
    }
    __syncthreads();
    // ao = v @ wo + bo
    {
        float po = 0.0f;
        #pragma unroll
        for (int kk = 0; kk < 4; ++kk) {
            int k = c * 4 + kk;
            po += vS[k] * W[MAWO + k * 32 + t];
        }
        pS[c][t] = po;
    }
    __syncthreads();
    if (tid < 32) {
        float o = W[MABO + t];
        #pragma unroll
        for (int cc = 0; cc < 8; ++cc) o += pS[cc][t];
        aoS[t] = o;
    }
    __syncthreads();

    // phase 2: tail for 64 agents, 8 per iteration
    for (int it = 0; it < 8; ++it) {
        const int a  = it * 8 + c;
        const int ba = b * 64 + a;
        float h  = outp[OUT_H + (size_t)ba * 32 + t];
        float x  = h + aoS[t];
        float sm = x;
        #pragma unroll
        for (int m2 = 1; m2 < 32; m2 <<= 1) sm += __shfl_xor(sm, m2, 64);
        float mean = sm * (1.0f / 32.0f);
        float dx = x - mean;
        float vv = dx * dx;
        #pragma unroll
        for (int m2 = 1; m2 < 32; m2 <<= 1) vv += __shfl_xor(vv, m2, 64);
        float var   = vv * (1.0f / 32.0f);
        float after = dx * rsqrtf(var + 1e-5f) * W[LN2G + t] + W[LN2B + t];

        WB();   // prior-iteration float4 reads of featS done before overwrite
        featS[c][t]      = h;
        featS[c][32 + t] = after;
        WB();   // half-wave-private: same-wave DS ordering, no block barrier
        float qe = W[QSB + t];
        {
            const float4* fF = (const float4*)&featS[c][0];
            #pragma unroll
            for (int q4 = 0; q4 < 16; ++q4) {
                float4 v = fF[q4];
                h2 a2 = pk2(v.x, v.y), b2 = pk2(v.z, v.w);
                qe = FD(a2, u2h(Wu[QSWP + (q4*2)*32 + t]), qe);
                qe = FD(b2, u2h(Wu[QSWP + (q4*2+1)*32 + t]), qe);
            }
        }
        qe = fmaxf(qe, 0.0f);
        WB();
        qeS[c][t] = qe;
        WB();
        if (t < 16) {
            const float4* qF = (const float4*)&qeS[c][0];
            float qa = W[AHB + a * 16 + t];
            #pragma unroll
            for (int q4 = 0; q4 < 8; ++q4) {
                float4 v = qF[q4];
                h2 a2 = pk2(v.x, v.y), b2 = pk2(v.z, v.w);
                qa = FD(a2, u2h(Wu[AHWP + a*256 + (q4*2)*16 + t]), qa);
                qa = FD(b2, u2h(Wu[AHWP + a*256 + (q4*2+1)*16 + t]), qa);
            }
            outp[OUT_Q + (size_t)ba * 16 + t] = qa;
        }
    }
}

extern "C" void kernel_launch(void* const* d_in, const int* in_sizes, int n_in,
                              void* d_out, int out_size, void* d_ws, size_t ws_size,
                              hipStream_t stream) {
    (void)in_sizes; (void)n_in; (void)out_size; (void)ws_size;
    WP wp;
    for (int i = 0; i < 30; ++i) wp.p[i] = (const float*)d_in[i + 2];

    float* W = (float*)d_ws;

    const float* states = (const float*)d_in[0];
    const float* hidden = (const float*)d_in[1];
    float* outp = (float*)d_out;

    kw_conv<<<dim3((W_TOTAL + 255) / 256), dim3(256), 0, stream>>>(wp, W);
    k_main<<<dim3(8192), dim3(256), 0, stream>>>(states, hidden, W, outp);
    k_tail2<<<dim3(1024), dim3(256), 0, stream>>>(W, outp);
}

// Round 3
// 481.476 us; speedup vs baseline: 1.0095x; 1.0095x over previous
//
#include <hip/hip_runtime.h>

typedef unsigned int u32;
typedef _Float16 f16;
typedef f16 h2 __attribute__((ext_vector_type(2)));

// ---------------- packed-weight ws layout (u32/f32 element offsets) ----------
#define QP     0        // [e<32][i<8] half2 pairs over f           (256)
#define KVP    256      // [e<64][i<8]                              (512)
#define WOP    768      // [f<16][i<16] pairs over e                (256)
#define ILWP   1024     // [(jp4<64 *32 + t)*4 + i] pairs over j    (8192)
#define WIHP   9216     // [(kp<16 *32 + t)*4 + j] j<3 used         (2048)
#define WHHP   11264    //                                          (2048)
#define MSWP   13312    // [kp<16 *32 + t]                          (512)
#define MGWP   13824    // [a*512 + kp<16 *32 + m]                  (32768)
#define QSWP   46592    // [kp<32 *32 + t]                          (1024)
#define AHWP   47616    // [a*256 + kp<16 *16 + u]                  (16384)
#define F32B   64000
#define BQ     (F32B+0)     // 32
#define BKV    (F32B+32)    // 64
#define BO     (F32B+96)    // 16
#define LN1G   (F32B+112)   // 16
#define LN1B   (F32B+128)   // 16
#define ILB    (F32B+144)   // 32
#define BIH    (F32B+176)   // 96
#define BHH    (F32B+272)   // 96
#define MSB    (F32B+368)   // 32
#define MGB    (F32B+400)   // 2048
#define MAWKVV (F32B+2448)  // 1024  wkv_V as [k<32][t<32]
#define MABKVV (F32B+3472)  // 32
#define MAWO   (F32B+3504)  // 1024
#define MABO   (F32B+4528)  // 32
#define LN2G   (F32B+4560)  // 32
#define LN2B   (F32B+4592)  // 32
#define QSB    (F32B+4624)  // 32
#define AHB    (F32B+4656)  // 1024
#define W_TOTAL (F32B+5680)
#define W_ALLOC 69696

// output element offsets (f32): q_values | h | mean_message
#define OUT_Q  0
#define OUT_H  1048576
#define OUT_MM 3145728

// softmax scale folded into wq/bq at repack time, in exp2 domain:
// CS = (1/sqrt(8)) * log2(e); score' = CS*(Q.K)  =>  exp(score*scale) = 2^score'
#define CS (0.35355339059327373f * 1.4426950408889634f)

// zero-cost compiler code-motion fence: guards type-punned LDS overlays
// (hardware same-wave DS ordering is already in-order; this only stops
// clang TBAA from reordering float vs uint4/float4 accesses to aliases)
#if __has_builtin(__builtin_amdgcn_wave_barrier)
#define WB() __builtin_amdgcn_wave_barrier()
#else
#define WB() __threadfence_block()
#endif

#if __has_builtin(__builtin_amdgcn_exp2f)
__device__ __forceinline__ float EXP2(float x) { return __builtin_amdgcn_exp2f(x); }
#else
__device__ __forceinline__ float EXP2(float x) { return __expf(x * 0.6931471805599453f); }
#endif

#if __has_builtin(__builtin_amdgcn_fdot2)
__device__ __forceinline__ float FD(h2 a, h2 b, float c) {
    return __builtin_amdgcn_fdot2(a, b, c, false);
}
#else
__device__ __forceinline__ float FD(h2 a, h2 b, float c) {
    return c + (float)a.x * (float)b.x + (float)a.y * (float)b.y;
}
#endif

#if __has_builtin(__builtin_amdgcn_cvt_pkrtz)
__device__ __forceinline__ h2 pk2(float a, float b) {
    auto r = __builtin_amdgcn_cvt_pkrtz(a, b);   // __fp16 vec2 on this clang
    h2 out;
    __builtin_memcpy(&out, &r, sizeof(out));      // no-op bitcast
    return out;
}
#else
__device__ __forceinline__ h2 pk2(float a, float b) { h2 r; r.x = (f16)a; r.y = (f16)b; return r; }
#endif

__device__ __forceinline__ h2  u2h(u32 x) { union { u32 u; h2 h; } c; c.u = x; return c.h; }
__device__ __forceinline__ u32 h2u(h2 x)  { union { u32 u; h2 h; } c; c.h = x; return c.u; }

__device__ __forceinline__ float sigm(float x) { return 1.0f / (1.0f + __expf(-x)); }

struct WP { const float* p[30]; };

// K0: repack weights: f16 pairs (packed along contraction dim) + f32 tail
__global__ void kw_conv(WP wp, float* W) {
    u32* Wu = (u32*)W;
    int gid = blockIdx.x * blockDim.x + threadIdx.x;
    if (gid >= W_TOTAL) return;
    if (gid < KVP) {                       // QP: ia_wq [16][32]  (x CS fold)
        int e = gid >> 3, i = gid & 7;
        const float* wq = wp.p[0];
        Wu[gid] = h2u(pk2(wq[(2*i)*32 + e] * CS, wq[(2*i+1)*32 + e] * CS));
    } else if (gid < WOP) {                // KVP: ia_wkv [16][64]
        int idx = gid - KVP; int e = idx >> 3, i = idx & 7;
        const float* wkv = wp.p[2];
        Wu[gid] = h2u(pk2(wkv[(2*i)*64 + e], wkv[(2*i+1)*64 + e]));
    } else if (gid < ILWP) {               // WOP: ia_wo [32][16]
        int idx = gid - WOP; int f = idx >> 4, i = idx & 15;
        const float* wo = wp.p[4];
        Wu[gid] = h2u(pk2(wo[(2*i)*16 + f], wo[(2*i+1)*16 + f]));
    } else if (gid < WIHP) {               // ILWP: il_w [512][32]
        int idx = gid - ILWP;
        int jp4 = idx >> 7, t = (idx >> 2) & 31, i = idx & 3;
        int jp = jp4 * 4 + i;
        const float* ilw = wp.p[8];
        Wu[gid] = h2u(pk2(ilw[(2*jp)*32 + t], ilw[(2*jp+1)*32 + t]));
    } else if (gid < WHHP) {               // WIHP: gru_wih [32][96]
        int idx = gid - WIHP;
        int kp = idx >> 7, t = (idx >> 2) & 31, j = idx & 3;
        const float* wih = wp.p[10];
        Wu[gid] = (j < 3) ? h2u(pk2(wih[(2*kp)*96 + j*32 + t], wih[(2*kp+1)*96 + j*32 + t])) : 0u;
    } else if (gid < MSWP) {               // WHHP: gru_whh [32][96]
        int idx = gid - WHHP;
        int kp = idx >> 7, t = (idx >> 2) & 31, j = idx & 3;
        const float* whh = wp.p[11];
        Wu[gid] = (j < 3) ? h2u(pk2(whh[(2*kp)*96 + j*32 + t], whh[(2*kp+1)*96 + j*32 + t])) : 0u;
    } else if (gid < MGWP) {               // MSWP: ms_w [32][32]
        int idx = gid - MSWP; int kp = idx >> 5, t = idx & 31;
        const float* msw = wp.p[14];
        Wu[gid] = h2u(pk2(msw[(2*kp)*32 + t], msw[(2*kp+1)*32 + t]));
    } else if (gid < QSWP) {               // MGWP: mg_w [64][32][32]
        int idx = gid - MGWP; int a = idx >> 9, rem = idx & 511, kp = rem >> 5, m = rem & 31;
        const float* mgw = wp.p[16];
        Wu[gid] = h2u(pk2(mgw[(a*32 + 2*kp)*32 + m], mgw[(a*32 + 2*kp+1)*32 + m]));
    } else if (gid < AHWP) {               // QSWP: qs_w [64][32]
        int idx = gid - QSWP; int kp = idx >> 5, t = idx & 31;
        const float* qsw = wp.p[26];
        Wu[gid] = h2u(pk2(qsw[(2*kp)*32 + t], qsw[(2*kp+1)*32 + t]));
    } else if (gid < F32B) {               // AHWP: ah_w [64][32][16]
        int idx = gid - AHWP; int a = idx >> 8, rem = idx & 255, kp = rem >> 4, u = rem & 15;
        const float* ahw = wp.p[28];
        Wu[gid] = h2u(pk2(ahw[(a*32 + 2*kp)*16 + u], ahw[(a*32 + 2*kp+1)*16 + u]));
    } else {                               // f32 tail
        int i = gid - F32B;
        float v;
        if      (i < 32)   v = wp.p[1][i] * CS;            // bq (x CS fold)
        else if (i < 96)   v = wp.p[3][i - 32];            // bkv
        else if (i < 112)  v = wp.p[5][i - 96];            // bo
        else if (i < 128)  v = wp.p[6][i - 112];           // ln1_g
        else if (i < 144)  v = wp.p[7][i - 128];           // ln1_b
        else if (i < 176)  v = wp.p[9][i - 144];           // il_b
        else if (i < 272)  v = wp.p[12][i - 176];          // gru_bih
        else if (i < 368)  v = wp.p[13][i - 272];          // gru_bhh
        else if (i < 400)  v = wp.p[15][i - 368];          // ms_b
        else if (i < 2448) v = wp.p[17][i - 400];          // mg_b
        else if (i < 3472) { int j = i - 2448; v = wp.p[20][(j >> 5)*64 + 32 + (j & 31)]; } // ma_wkv V
        else if (i < 3504) v = wp.p[21][32 + (i - 3472)];  // ma_bkv V
        else if (i < 4528) v = wp.p[22][i - 3504];         // ma_wo
        else if (i < 4560) v = wp.p[23][i - 4528];         // ma_bo
        else if (i < 4592) v = wp.p[24][i - 4560];         // ln2_g
        else if (i < 4624) v = wp.p[25][i - 4592];         // ln2_b
        else if (i < 4656) v = wp.p[27][i - 4624];         // qs_b
        else               v = wp.p[29][i - 4656];         // ah_b
        W[gid] = v;
    }
}

// K1: per wave = 2 agents. lane = (sub<<5)|t ; t = link/row index.
// ALL LDS regions are wave-private ([ag] with ag owned by the wave), so no
// __syncthreads is needed anywhere: same-wave DS ops execute in order at the
// hardware level; WB() (zero-instruction wave_barrier) pins the compiler's
// memory-op order at every type-punned overlay transition.
// LDS exactly 32 KiB. Scratch (enc/hn/memb) overlays VbH[ag] (dead after P2);
// h is re-read from global (L1-warm). launch_bounds (256,4): 128-VGPR cap —
// round-2's (,5) saw the allocator squeeze to 48 VGPRs (remat pressure).
__global__ __launch_bounds__(256, 4) void k_main(
    const float* __restrict__ states, const float* __restrict__ hidden,
    const float* W, float* __restrict__ outp)
{
    const u32* Wu = (const u32*)W;

    __shared__ uint4 KbH[8][32][4];   // f16 K rows (swizzled); later: aft rows
    __shared__ uint4 VbH[8][32][4];   // f16 V rows (swizzled); later: scratch

    const int w    = threadIdx.x >> 6;
    const int lane = threadIdx.x & 63;
    const int sub  = lane >> 5;
    const int t    = lane & 31;
    const int ag   = w * 2 + sub;
    const int pair = blockIdx.x * 4 + w;
    const int b    = pair >> 5;
    const int a    = ((pair & 31) << 1) | sub;
    const int ba   = b * 64 + a;

    float* scr = (float*)&VbH[ag][0][0];   // 512 f32; [0..31]=enc [64..95]=hn [96..127]=memb

    // ---- P0: states row (link t): 16 f32; hidden value (latency overlap) ----
    float s[16];
    {
        const float4* p4 = reinterpret_cast<const float4*>(states + ((size_t)ba * 32 + t) * 16);
        float4 f0 = p4[0], f1 = p4[1], f2 = p4[2], f3 = p4[3];
        s[0]=f0.x; s[1]=f0.y; s[2]=f0.z; s[3]=f0.w;
        s[4]=f1.x; s[5]=f1.y; s[6]=f1.z; s[7]=f1.w;
        s[8]=f2.x; s[9]=f2.y; s[10]=f2.z; s[11]=f2.w;
        s[12]=f3.x; s[13]=f3.y; s[14]=f3.z; s[15]=f3.w;
    }
    float hp = hidden[(size_t)ba * 32 + t];
    h2 sh[8];
    #pragma unroll
    for (int i = 0; i < 8; ++i) sh[i] = pk2(s[2*i], s[2*i+1]);

    // ---- P1a: Q (packed pairs; weights wave-uniform -> s_load). wq/bq carry
    //           the CS = scale*log2e fold, so scores land in exp2 domain. ----
    h2 qh[16];
    #pragma unroll
    for (int j = 0; j < 16; ++j) {
        float a0 = W[BQ + 2*j], a1 = W[BQ + 2*j + 1];
        #pragma unroll
        for (int i = 0; i < 8; ++i) {
            a0 = FD(sh[i], u2h(Wu[QP + (2*j)*8 + i]), a0);
            a1 = FD(sh[i], u2h(Wu[QP + (2*j+1)*8 + i]), a1);
        }
        qh[j] = pk2(a0, a1);
    }
    // ---- P1b: K,V rows -> f16 LDS (swizzled cols) ----
    #pragma unroll
    for (int u = 0; u < 4; ++u) {
        u32 kc[4], vc[4];
        #pragma unroll
        for (int c = 0; c < 4; ++c) {
            int e0 = u*8 + 2*c, e1 = e0 + 1;
            float k0 = W[BKV+e0], k1 = W[BKV+e1];
            float v0 = W[BKV+32+e0], v1 = W[BKV+32+e1];
            #pragma unroll
            for (int i = 0; i < 8; ++i) {
                k0 = FD(sh[i], u2h(Wu[KVP + e0*8 + i]), k0);
                k1 = FD(sh[i], u2h(Wu[KVP + e1*8 + i]), k1);
                v0 = FD(sh[i], u2h(Wu[KVP + (32+e0)*8 + i]), v0);
                v1 = FD(sh[i], u2h(Wu[KVP + (32+e1)*8 + i]), v1);
            }
            kc[c] = h2u(pk2(k0, k1)); vc[c] = h2u(pk2(v0, v1));
        }
        int uc = u ^ (t & 3);
        KbH[ag][t][uc] = make_uint4(kc[0], kc[1], kc[2], kc[3]);
        VbH[ag][t][uc] = make_uint4(vc[0], vc[1], vc[2], vc[3]);
    }
    WB();   // K/V writes ordered before P2 reads (same wave, in-order DS pipe)

    // ---- P2: 4-head attention; fused score+PV loop (no scf array);
    //          e = exp2(sc) (scale pre-folded); PV in packed f16 ----
    h2 oh[16];
    #pragma unroll
    for (int hh = 0; hh < 4; ++hh) {
        float l = 0.0f;
        h2 ov0 = {(f16)0, (f16)0}, ov1 = ov0, ov2 = ov0, ov3 = ov0;
        #pragma unroll
        for (int k = 0; k < 32; ++k) {
            uint4 kr = KbH[ag][k][hh ^ (k & 3)];   // uniform addr -> broadcast
            float sc = 0.0f;
            sc = FD(qh[hh*4+0], u2h(kr.x), sc);
            sc = FD(qh[hh*4+1], u2h(kr.y), sc);
            sc = FD(qh[hh*4+2], u2h(kr.z), sc);
            sc = FD(qh[hh*4+3], u2h(kr.w), sc);
            float e = EXP2(sc);
            l += e;
            h2 ph = pk2(e, e);
            uint4 vr = VbH[ag][k][hh ^ (k & 3)];
            ov0 += ph * u2h(vr.x);
            ov1 += ph * u2h(vr.y);
            ov2 += ph * u2h(vr.z);
            ov3 += ph * u2h(vr.w);
        }
        float inv = 1.0f / l;
        h2 hinv = pk2(inv, inv);
        oh[hh*4+0] = ov0 * hinv; oh[hh*4+1] = ov1 * hinv;
        oh[hh*4+2] = ov2 * hinv; oh[hh*4+3] = ov3 * hinv;
    }
    WB();   // all KbH/VbH reads complete-in-order before overlay writes below

    // ---- P3: out proj + residual + LayerNorm(16) ----
    float aft[16];
    {
        float x[16];
        float mean = 0.0f;
        #pragma unroll
        for (int f = 0; f < 16; ++f) {
            float acc = W[BO + f];
            #pragma unroll
            for (int i = 0; i < 16; ++i) acc = FD(oh[i], u2h(Wu[WOP + f*16 + i]), acc);
            x[f] = s[f] + acc;
            mean += x[f];
        }
        mean *= (1.0f / 16.0f);
        float var = 0.0f;
        #pragma unroll
        for (int f = 0; f < 16; ++f) { float d = x[f] - mean; var += d * d; }
        var *= (1.0f / 16.0f);
        float rs = rsqrtf(var + 1e-5f);
        #pragma unroll
        for (int f = 0; f < 16; ++f)
            aft[f] = (x[f] - mean) * rs * W[LN1G + f] + W[LN1B + f];
    }
    // aft rows -> LDS, overlaying KbH[ag] (dead after P2; ordered by WB above)
    uint4* aftA = &KbH[ag][0][0];   // 64 uint4 per ag-group
    {
        u32 ac[8];
        #pragma unroll
        for (int c = 0; c < 8; ++c) ac[c] = h2u(pk2(aft[2*c], aft[2*c+1]));
        aftA[2*t]     = make_uint4(ac[0], ac[1], ac[2], ac[3]);
        aftA[2*t + 1] = make_uint4(ac[4], ac[5], ac[6], ac[7]);
    }
    WB();   // aft writes ordered before P4 reads

    // ---- P4: enc[t] = il_b[t] + aft_flat . il_w[:,t]  (f16 dot2) ----
    float enc = W[ILB + t];
    {
        const uint4* aA   = aftA;
        const uint4* ilw4 = (const uint4*)(Wu + ILWP);
        #pragma unroll 8
        for (int jp4 = 0; jp4 < 64; ++jp4) {
            uint4 av = aA[jp4];
            uint4 wv = ilw4[jp4 * 32 + t];
            enc = FD(u2h(av.x), u2h(wv.x), enc);
            enc = FD(u2h(av.y), u2h(wv.y), enc);
            enc = FD(u2h(av.z), u2h(wv.z), enc);
            enc = FD(u2h(av.w), u2h(wv.w), enc);
        }
    }
    WB();
    scr[t] = enc;   // overlays VbH[ag] (dead after P2; WB-fenced)
    WB();

    // ---- P5: GRU (h row re-read from global: uniform f4 broadcast, L1-warm) ----
    float gi0 = W[BIH + t], gi1 = W[BIH + 32 + t], gi2 = W[BIH + 64 + t];
    float gh0 = W[BHH + t], gh1 = W[BHH + 32 + t], gh2 = W[BHH + 64 + t];
    {
        const float4* eF = (const float4*)scr;
        const float4* hF = (const float4*)(hidden + (size_t)ba * 32);
        const uint4* wi4 = (const uint4*)(Wu + WIHP);
        const uint4* wh4 = (const uint4*)(Wu + WHHP);
        #pragma unroll
        for (int q4 = 0; q4 < 8; ++q4) {
            float4 ev = eF[q4], hv = hF[q4];
            h2 ea = pk2(ev.x, ev.y), eb = pk2(ev.z, ev.w);
            h2 ha = pk2(hv.x, hv.y), hb = pk2(hv.z, hv.w);
            uint4 wiA = wi4[(q4*2)*32 + t], wiB = wi4[(q4*2+1)*32 + t];
            uint4 whA = wh4[(q4*2)*32 + t], whB = wh4[(q4*2+1)*32 + t];
            gi0 = FD(ea, u2h(wiA.x), gi0); gi1 = FD(ea, u2h(wiA.y), gi1); gi2 = FD(ea, u2h(wiA.z), gi2);
            gi0 = FD(eb, u2h(wiB.x), gi0); gi1 = FD(eb, u2h(wiB.y), gi1); gi2 = FD(eb, u2h(wiB.z), gi2);
            gh0 = FD(ha, u2h(whA.x), gh0); gh1 = FD(ha, u2h(whA.y), gh1); gh2 = FD(ha, u2h(whA.z), gh2);
            gh0 = FD(hb, u2h(whB.x), gh0); gh1 = FD(hb, u2h(whB.y), gh1); gh2 = FD(hb, u2h(whB.z), gh2);
        }
    }
    float r  = sigm(gi0 + gh0);
    float z  = sigm(gi1 + gh1);
    float n  = tanhf(gi2 + r * gh2);
    float hn = (1.0f - z) * n + z * hp;
    outp[OUT_H + (size_t)ba * 32 + t] = hn;
    WB();
    scr[64 + t] = hn;
    WB();

    // ---- P6: memb = relu(h @ ms_w + b); msg = memb @ mg_w[a] + b ----
    {
        const float4* nF = (const float4*)(scr + 64);
        float mb = W[MSB + t];
        #pragma unroll
        for (int q4 = 0; q4 < 8; ++q4) {
            float4 v = nF[q4];
            h2 a2 = pk2(v.x, v.y), b2 = pk2(v.z, v.w);
            mb = FD(a2, u2h(Wu[MSWP + (q4*2)*32 + t]), mb);
            mb = FD(b2, u2h(Wu[MSWP + (q4*2+1)*32 + t]), mb);
        }
        mb = fmaxf(mb, 0.0f);
        WB();
        scr[96 + t] = mb;
        WB();
    }
    {
        const float4* mF = (const float4*)(scr + 96);
        float mg = W[MGB + a * 32 + t];
        #pragma unroll
        for (int q4 = 0; q4 < 8; ++q4) {
            float4 v = mF[q4];
            h2 a2 = pk2(v.x, v.y), b2 = pk2(v.z, v.w);
            mg = FD(a2, u2h(Wu[MGWP + a*512 + (q4*2)*32 + t]), mg);
            mg = FD(b2, u2h(Wu[MGWP + a*512 + (q4*2+1)*32 + t]), mg);
        }
        // stash raw per-agent message; k_mean overwrites with the mean
        outp[OUT_MM + (size_t)ba * 32 + t] = mg;
    }
}

// K2: per-batch message mean (in-place over OUT_MM) + degenerate comm-attn
// (sl=1 => softmax==1 => ao = (mm @ wkv_V + bkv_V) @ wo + bo, per batch).
// Both 32x32 matvecs 8-way parallelized across half-waves.
__global__ __launch_bounds__(256) void k_mean(const float* W, float* __restrict__ ao_ws,
                                              float* __restrict__ outp)
{
    const int b   = blockIdx.x;
    const int tid = threadIdx.x;
    const int t   = tid & 31;
    const int c   = tid >> 5;        // 0..7
    __shared__ float pS[8][32];
    __shared__ float mmS[32];
    __shared__ float vS[32];

    // mean over 64 agents (8-way partials)
    float acc = 0.0f;
    #pragma unroll
    for (int a2 = 0; a2 < 8; ++a2)
        acc += outp[OUT_MM + ((size_t)b * 64 + (a2 * 8 + c)) * 32 + t];
    pS[c][t] = acc;
    __syncthreads();
    if (tid < 32) {
        float ssum = 0.0f;
        #pragma unroll
        for (int cc = 0; cc < 8; ++cc) ssum += pS[cc][t];
        mmS[t] = ssum * (1.0f / 64.0f);
    }
    __syncthreads();
    // write mean_message output (broadcast to all 64 agents)
    {
        float mv = mmS[t];
        for (int i = tid; i < 2048; i += 256)
            outp[OUT_MM + (size_t)b * 2048 + i] = mv;   // i & 31 == t
    }
    // v = mm @ wkv_V + bkv_V  (each half-wave covers 4 k's)
    {
        float pv = 0.0f;
        #pragma unroll
        for (int kk = 0; kk < 4; ++kk) {
            int k = c * 4 + kk;
            pv += mmS[k] * W[MAWKVV + k * 32 + t];
        }
        pS[c][t] = pv;
    }
    __syncthreads();
    if (tid < 32) {
        float v = W[MABKVV + t];
        #pragma unroll
        for (int cc = 0; cc < 8; ++cc) v += pS[cc][t];
        vS[t] = v;
    }
    __syncthreads();
    // ao = v @ wo + bo
    {
        float po = 0.0f;
        #pragma unroll
        for (int kk = 0; kk < 4; ++kk) {
            int k = c * 4 + kk;
            po += vS[k] * W[MAWO + k * 32 + t];
        }
        pS[c][t] = po;
    }
    __syncthreads();
    if (tid < 32) {
        float o = W[MABO + t];
        #pragma unroll
        for (int cc = 0; cc < 8; ++cc) o += pS[cc][t];
        ao_ws[b * 32 + t] = o;
    }
}

// K3: LN2(h + ao[b]) -> feat=[h,after] -> relu(qs) -> per-agent Q head.
// 8192 blocks (one agent per half-wave slot) — all h loads issue in parallel.
// featS/qeS are half-wave-private ([ag]) -> WB() fences, no block barriers.
__global__ __launch_bounds__(256) void k_tail(
    const float* __restrict__ ao_ws, const float* W, float* __restrict__ outp)
{
    const u32* Wu = (const u32*)W;
    __shared__ __align__(16) float featS[8][64];
    __shared__ __align__(16) float qeS[8][32];
    const int w    = threadIdx.x >> 6;
    const int lane = threadIdx.x & 63;
    const int sub  = lane >> 5;
    const int t    = lane & 31;
    const int ag   = w * 2 + sub;
    const int pair = blockIdx.x * 4 + w;
    const int b    = pair >> 5;
    const int a    = ((pair & 31) << 1) | sub;
    const int ba   = b * 64 + a;

    float h  = outp[OUT_H + (size_t)ba * 32 + t];
    float ao = ao_ws[b * 32 + t];
    float x  = h + ao;
    float sm = x;
    #pragma unroll
    for (int m2 = 1; m2 < 32; m2 <<= 1) sm += __shfl_xor(sm, m2, 64);
    float mean = sm * (1.0f / 32.0f);
    float dx = x - mean;
    float vv = dx * dx;
    #pragma unroll
    for (int m2 = 1; m2 < 32; m2 <<= 1) vv += __shfl_xor(vv, m2, 64);
    float var   = vv * (1.0f / 32.0f);
    float after = dx * rsqrtf(var + 1e-5f) * W[LN2G + t] + W[LN2B + t];

    featS[ag][t]      = h;
    featS[ag][32 + t] = after;
    WB();   // half-wave-private: same-wave DS ordering, no block barrier
    {
        const float4* fF = (const float4*)&featS[ag][0];
        float acc = W[QSB + t];
        #pragma unroll
        for (int q4 = 0; q4 < 16; ++q4) {
            float4 v = fF[q4];
            h2 a2 = pk2(v.x, v.y), b2 = pk2(v.z, v.w);
            acc = FD(a2, u2h(Wu[QSWP + (q4*2)*32 + t]), acc);
            acc = FD(b2, u2h(Wu[QSWP + (q4*2+1)*32 + t]), acc);
        }
        acc = fmaxf(acc, 0.0f);
        WB();
        qeS[ag][t] = acc;
        WB();
    }
    if (t < 16) {
        const float4* qF = (const float4*)&qeS[ag][0];
        float qa = W[AHB + a * 16 + t];
        #pragma unroll
        for (int q4 = 0; q4 < 8; ++q4) {
            float4 v = qF[q4];
            h2 a2 = pk2(v.x, v.y), b2 = pk2(v.z, v.w);
            qa = FD(a2, u2h(Wu[AHWP + a*256 + (q4*2)*16 + t]), qa);
            qa = FD(b2, u2h(Wu[AHWP + a*256 + (q4*2+1)*16 + t]), qa);
        }
        outp[OUT_Q + (size_t)ba * 16 + t] = qa;
    }
}

extern "C" void kernel_launch(void* const* d_in, const int* in_sizes, int n_in,
                              void* d_out, int out_size, void* d_ws, size_t ws_size,
                              hipStream_t stream) {
    (void)in_sizes; (void)n_in; (void)out_size; (void)ws_size;
    WP wp;
    for (int i = 0; i < 30; ++i) wp.p[i] = (const float*)d_in[i + 2];

    float* W     = (float*)d_ws;
    float* ao_ws = W + W_ALLOC;   // 1024*32 f32

    const float* states = (const float*)d_in[0];
    const float* hidden = (const float*)d_in[1];
    float* outp = (float*)d_out;

    kw_conv<<<dim3((W_TOTAL + 255) / 256), dim3(256), 0, stream>>>(wp, W);
    k_main<<<dim3(8192), dim3(256), 0, stream>>>(states, hidden, W, outp);
    k_mean<<<dim3(1024), dim3(256), 0, stream>>>(W, ao_ws, outp);
    k_tail<<<dim3(8192), dim3(256), 0, stream>>>(ao_ws, W, outp);
}

// Round 4
// 446.314 us; speedup vs baseline: 1.0891x; 1.0788x over previous
//
#include <hip/hip_runtime.h>

typedef unsigned int u32;
typedef _Float16 f16;
typedef f16 h2 __attribute__((ext_vector_type(2)));

// ---------------- packed-weight ws layout (u32/f32 element offsets) ----------
#define QP     0        // [e<32][i<8] half2 pairs over f           (256)
#define KVP    256      // [e<64][i<8]                              (512)
#define WOP    768      // [f<16][i<16] pairs over e                (256)
#define ILWP   1024     // [(jp4<64 *32 + t)*4 + i] pairs over j    (8192)
#define WIHP   9216     // [(kp<16 *32 + t)*4 + j] j<3 used         (2048)
#define WHHP   11264    //                                          (2048)
#define MSWP   13312    // [kp<16 *32 + t]                          (512)
#define MGWP   13824    // [a*512 + kp<16 *32 + m]                  (32768)
#define QSWP   46592    // [kp<32 *32 + t]                          (1024)
#define AHWP   47616    // [a*256 + kp<16 *16 + u]                  (16384)
#define F32B   64000
#define BQ     (F32B+0)     // 32
#define BKV    (F32B+32)    // 64
#define BO     (F32B+96)    // 16
#define LN1G   (F32B+112)   // 16
#define LN1B   (F32B+128)   // 16
#define ILB    (F32B+144)   // 32
#define BIH    (F32B+176)   // 96
#define BHH    (F32B+272)   // 96
#define MSB    (F32B+368)   // 32
#define MGB    (F32B+400)   // 2048
#define MAWKVV (F32B+2448)  // 1024  wkv_V as [k<32][t<32]
#define MABKVV (F32B+3472)  // 32
#define MAWO   (F32B+3504)  // 1024
#define MABO   (F32B+4528)  // 32
#define LN2G   (F32B+4560)  // 32
#define LN2B   (F32B+4592)  // 32
#define QSB    (F32B+4624)  // 32
#define AHB    (F32B+4656)  // 1024
#define W_TOTAL (F32B+5680)
#define W_ALLOC 69696

// output element offsets (f32): q_values | h | mean_message
#define OUT_Q  0
#define OUT_H  1048576
#define OUT_MM 3145728

// softmax scale folded into wq/bq at repack time, in exp2 domain:
// CS = (1/sqrt(8)) * log2(e); score' = CS*(Q.K)  =>  exp(score*scale) = 2^score'
#define CS (0.35355339059327373f * 1.4426950408889634f)

// zero-cost compiler code-motion fence: guards type-punned LDS overlays
// (hardware same-wave DS ordering is already in-order; this only stops
// clang TBAA from reordering float vs uint4/float4 accesses to aliases)
#if __has_builtin(__builtin_amdgcn_wave_barrier)
#define WB() __builtin_amdgcn_wave_barrier()
#else
#define WB() __threadfence_block()
#endif

#if __has_builtin(__builtin_amdgcn_exp2f)
__device__ __forceinline__ float EXP2(float x) { return __builtin_amdgcn_exp2f(x); }
#else
__device__ __forceinline__ float EXP2(float x) { return __expf(x * 0.6931471805599453f); }
#endif

#if __has_builtin(__builtin_amdgcn_fdot2)
__device__ __forceinline__ float FD(h2 a, h2 b, float c) {
    return __builtin_amdgcn_fdot2(a, b, c, false);
}
#else
__device__ __forceinline__ float FD(h2 a, h2 b, float c) {
    return c + (float)a.x * (float)b.x + (float)a.y * (float)b.y;
}
#endif

#if __has_builtin(__builtin_amdgcn_cvt_pkrtz)
__device__ __forceinline__ h2 pk2(float a, float b) {
    auto r = __builtin_amdgcn_cvt_pkrtz(a, b);   // __fp16 vec2 on this clang
    h2 out;
    __builtin_memcpy(&out, &r, sizeof(out));      // no-op bitcast
    return out;
}
#else
__device__ __forceinline__ h2 pk2(float a, float b) { h2 r; r.x = (f16)a; r.y = (f16)b; return r; }
#endif

__device__ __forceinline__ h2  u2h(u32 x) { union { u32 u; h2 h; } c; c.u = x; return c.h; }
__device__ __forceinline__ u32 h2u(h2 x)  { union { u32 u; h2 h; } c; c.h = x; return c.u; }

__device__ __forceinline__ float sigm(float x) { return 1.0f / (1.0f + __expf(-x)); }

struct WP { const float* p[30]; };

// K0: repack weights: f16 pairs (packed along contraction dim) + f32 tail
__global__ void kw_conv(WP wp, float* W) {
    u32* Wu = (u32*)W;
    int gid = blockIdx.x * blockDim.x + threadIdx.x;
    if (gid >= W_TOTAL) return;
    if (gid < KVP) {                       // QP: ia_wq [16][32]  (x CS fold)
        int e = gid >> 3, i = gid & 7;
        const float* wq = wp.p[0];
        Wu[gid] = h2u(pk2(wq[(2*i)*32 + e] * CS, wq[(2*i+1)*32 + e] * CS));
    } else if (gid < WOP) {                // KVP: ia_wkv [16][64]
        int idx = gid - KVP; int e = idx >> 3, i = idx & 7;
        const float* wkv = wp.p[2];
        Wu[gid] = h2u(pk2(wkv[(2*i)*64 + e], wkv[(2*i+1)*64 + e]));
    } else if (gid < ILWP) {               // WOP: ia_wo [32][16]
        int idx = gid - WOP; int f = idx >> 4, i = idx & 15;
        const float* wo = wp.p[4];
        Wu[gid] = h2u(pk2(wo[(2*i)*16 + f], wo[(2*i+1)*16 + f]));
    } else if (gid < WIHP) {               // ILWP: il_w [512][32]
        int idx = gid - ILWP;
        int jp4 = idx >> 7, t = (idx >> 2) & 31, i = idx & 3;
        int jp = jp4 * 4 + i;
        const float* ilw = wp.p[8];
        Wu[gid] = h2u(pk2(ilw[(2*jp)*32 + t], ilw[(2*jp+1)*32 + t]));
    } else if (gid < WHHP) {               // WIHP: gru_wih [32][96]
        int idx = gid - WIHP;
        int kp = idx >> 7, t = (idx >> 2) & 31, j = idx & 3;
        const float* wih = wp.p[10];
        Wu[gid] = (j < 3) ? h2u(pk2(wih[(2*kp)*96 + j*32 + t], wih[(2*kp+1)*96 + j*32 + t])) : 0u;
    } else if (gid < MSWP) {               // WHHP: gru_whh [32][96]
        int idx = gid - WHHP;
        int kp = idx >> 7, t = (idx >> 2) & 31, j = idx & 3;
        const float* whh = wp.p[11];
        Wu[gid] = (j < 3) ? h2u(pk2(whh[(2*kp)*96 + j*32 + t], whh[(2*kp+1)*96 + j*32 + t])) : 0u;
    } else if (gid < MGWP) {               // MSWP: ms_w [32][32]
        int idx = gid - MSWP; int kp = idx >> 5, t = idx & 31;
        const float* msw = wp.p[14];
        Wu[gid] = h2u(pk2(msw[(2*kp)*32 + t], msw[(2*kp+1)*32 + t]));
    } else if (gid < QSWP) {               // MGWP: mg_w [64][32][32]
        int idx = gid - MGWP; int a = idx >> 9, rem = idx & 511, kp = rem >> 5, m = rem & 31;
        const float* mgw = wp.p[16];
        Wu[gid] = h2u(pk2(mgw[(a*32 + 2*kp)*32 + m], mgw[(a*32 + 2*kp+1)*32 + m]));
    } else if (gid < AHWP) {               // QSWP: qs_w [64][32]
        int idx = gid - QSWP; int kp = idx >> 5, t = idx & 31;
        const float* qsw = wp.p[26];
        Wu[gid] = h2u(pk2(qsw[(2*kp)*32 + t], qsw[(2*kp+1)*32 + t]));
    } else if (gid < F32B) {               // AHWP: ah_w [64][32][16]
        int idx = gid - AHWP; int a = idx >> 8, rem = idx & 255, kp = rem >> 4, u = rem & 15;
        const float* ahw = wp.p[28];
        Wu[gid] = h2u(pk2(ahw[(a*32 + 2*kp)*16 + u], ahw[(a*32 + 2*kp+1)*16 + u]));
    } else {                               // f32 tail
        int i = gid - F32B;
        float v;
        if      (i < 32)   v = wp.p[1][i] * CS;            // bq (x CS fold)
        else if (i < 96)   v = wp.p[3][i - 32];            // bkv
        else if (i < 112)  v = wp.p[5][i - 96];            // bo
        else if (i < 128)  v = wp.p[6][i - 112];           // ln1_g
        else if (i < 144)  v = wp.p[7][i - 128];           // ln1_b
        else if (i < 176)  v = wp.p[9][i - 144];           // il_b
        else if (i < 272)  v = wp.p[12][i - 176];          // gru_bih
        else if (i < 368)  v = wp.p[13][i - 272];          // gru_bhh
        else if (i < 400)  v = wp.p[15][i - 368];          // ms_b
        else if (i < 2448) v = wp.p[17][i - 400];          // mg_b
        else if (i < 3472) { int j = i - 2448; v = wp.p[20][(j >> 5)*64 + 32 + (j & 31)]; } // ma_wkv V
        else if (i < 3504) v = wp.p[21][32 + (i - 3472)];  // ma_bkv V
        else if (i < 4528) v = wp.p[22][i - 3504];         // ma_wo
        else if (i < 4560) v = wp.p[23][i - 4528];         // ma_bo
        else if (i < 4592) v = wp.p[24][i - 4560];         // ln2_g
        else if (i < 4624) v = wp.p[25][i - 4592];         // ln2_b
        else if (i < 4656) v = wp.p[27][i - 4624];         // qs_b
        else               v = wp.p[29][i - 4656];         // ah_b
        W[gid] = v;
    }
}

// K1: per wave = 2 agents. lane = (sub<<5)|t ; t = link/row index.
// ALL LDS regions are wave-private ([ag] with ag owned by the wave), so no
// __syncthreads is needed anywhere: same-wave DS ops execute in order at the
// hardware level; WB() (zero-instruction wave_barrier) pins the compiler's
// memory-op order at every type-punned overlay transition.
// LDS exactly 32 KiB. Scratch (enc/hn/memb) overlays VbH[ag] (dead after P2);
// h is re-read from global (L1-warm).
// launch_bounds (256,5): MEASURED best — r2 (,5): 48 VGPR, zero scratch,
// WRITE=16MB, 264us. r0/r3 (,4): 64 VGPR + ~130B/thread scratch spill
// (WRITE 229-295MB, FETCH +90MB), 291-299us. Do not relax to (,4).
__global__ __launch_bounds__(256, 5) void k_main(
    const float* __restrict__ states, const float* __restrict__ hidden,
    const float* W, float* __restrict__ outp)
{
    const u32* Wu = (const u32*)W;

    __shared__ uint4 KbH[8][32][4];   // f16 K rows (swizzled); later: aft rows
    __shared__ uint4 VbH[8][32][4];   // f16 V rows (swizzled); later: scratch

    const int w    = threadIdx.x >> 6;
    const int lane = threadIdx.x & 63;
    const int sub  = lane >> 5;
    const int t    = lane & 31;
    const int ag   = w * 2 + sub;
    const int pair = blockIdx.x * 4 + w;
    const int b    = pair >> 5;
    const int a    = ((pair & 31) << 1) | sub;
    const int ba   = b * 64 + a;

    float* scr = (float*)&VbH[ag][0][0];   // 512 f32; [0..31]=enc [64..95]=hn [96..127]=memb

    // ---- P0: states row (link t): 16 f32; hidden value (latency overlap) ----
    float s[16];
    {
        const float4* p4 = reinterpret_cast<const float4*>(states + ((size_t)ba * 32 + t) * 16);
        float4 f0 = p4[0], f1 = p4[1], f2 = p4[2], f3 = p4[3];
        s[0]=f0.x; s[1]=f0.y; s[2]=f0.z; s[3]=f0.w;
        s[4]=f1.x; s[5]=f1.y; s[6]=f1.z; s[7]=f1.w;
        s[8]=f2.x; s[9]=f2.y; s[10]=f2.z; s[11]=f2.w;
        s[12]=f3.x; s[13]=f3.y; s[14]=f3.z; s[15]=f3.w;
    }
    float hp = hidden[(size_t)ba * 32 + t];
    h2 sh[8];
    #pragma unroll
    for (int i = 0; i < 8; ++i) sh[i] = pk2(s[2*i], s[2*i+1]);

    // ---- P1a: Q (packed pairs; weights wave-uniform -> s_load). wq/bq carry
    //           the CS = scale*log2e fold, so scores land in exp2 domain. ----
    h2 qh[16];
    #pragma unroll
    for (int j = 0; j < 16; ++j) {
        float a0 = W[BQ + 2*j], a1 = W[BQ + 2*j + 1];
        #pragma unroll
        for (int i = 0; i < 8; ++i) {
            a0 = FD(sh[i], u2h(Wu[QP + (2*j)*8 + i]), a0);
            a1 = FD(sh[i], u2h(Wu[QP + (2*j+1)*8 + i]), a1);
        }
        qh[j] = pk2(a0, a1);
    }
    // ---- P1b: K,V rows -> f16 LDS (swizzled cols) ----
    #pragma unroll
    for (int u = 0; u < 4; ++u) {
        u32 kc[4], vc[4];
        #pragma unroll
        for (int c = 0; c < 4; ++c) {
            int e0 = u*8 + 2*c, e1 = e0 + 1;
            float k0 = W[BKV+e0], k1 = W[BKV+e1];
            float v0 = W[BKV+32+e0], v1 = W[BKV+32+e1];
            #pragma unroll
            for (int i = 0; i < 8; ++i) {
                k0 = FD(sh[i], u2h(Wu[KVP + e0*8 + i]), k0);
                k1 = FD(sh[i], u2h(Wu[KVP + e1*8 + i]), k1);
                v0 = FD(sh[i], u2h(Wu[KVP + (32+e0)*8 + i]), v0);
                v1 = FD(sh[i], u2h(Wu[KVP + (32+e1)*8 + i]), v1);
            }
            kc[c] = h2u(pk2(k0, k1)); vc[c] = h2u(pk2(v0, v1));
        }
        int uc = u ^ (t & 3);
        KbH[ag][t][uc] = make_uint4(kc[0], kc[1], kc[2], kc[3]);
        VbH[ag][t][uc] = make_uint4(vc[0], vc[1], vc[2], vc[3]);
    }
    WB();   // K/V writes ordered before P2 reads (same wave, in-order DS pipe)

    // ---- P2: 4-head attention; fused score+PV loop (no scf array);
    //          e = exp2(sc) (scale pre-folded); PV in packed f16 ----
    h2 oh[16];
    #pragma unroll
    for (int hh = 0; hh < 4; ++hh) {
        float l = 0.0f;
        h2 ov0 = {(f16)0, (f16)0}, ov1 = ov0, ov2 = ov0, ov3 = ov0;
        #pragma unroll
        for (int k = 0; k < 32; ++k) {
            uint4 kr = KbH[ag][k][hh ^ (k & 3)];   // uniform addr -> broadcast
            float sc = 0.0f;
            sc = FD(qh[hh*4+0], u2h(kr.x), sc);
            sc = FD(qh[hh*4+1], u2h(kr.y), sc);
            sc = FD(qh[hh*4+2], u2h(kr.z), sc);
            sc = FD(qh[hh*4+3], u2h(kr.w), sc);
            float e = EXP2(sc);
            l += e;
            h2 ph = pk2(e, e);
            uint4 vr = VbH[ag][k][hh ^ (k & 3)];
            ov0 += ph * u2h(vr.x);
            ov1 += ph * u2h(vr.y);
            ov2 += ph * u2h(vr.z);
            ov3 += ph * u2h(vr.w);
        }
        float inv = 1.0f / l;
        h2 hinv = pk2(inv, inv);
        oh[hh*4+0] = ov0 * hinv; oh[hh*4+1] = ov1 * hinv;
        oh[hh*4+2] = ov2 * hinv; oh[hh*4+3] = ov3 * hinv;
    }
    WB();   // all KbH/VbH reads complete-in-order before overlay writes below

    // ---- P3: out proj + residual + LayerNorm(16) ----
    float aft[16];
    {
        float x[16];
        float mean = 0.0f;
        #pragma unroll
        for (int f = 0; f < 16; ++f) {
            float acc = W[BO + f];
            #pragma unroll
            for (int i = 0; i < 16; ++i) acc = FD(oh[i], u2h(Wu[WOP + f*16 + i]), acc);
            x[f] = s[f] + acc;
            mean += x[f];
        }
        mean *= (1.0f / 16.0f);
        float var = 0.0f;
        #pragma unroll
        for (int f = 0; f < 16; ++f) { float d = x[f] - mean; var += d * d; }
        var *= (1.0f / 16.0f);
        float rs = rsqrtf(var + 1e-5f);
        #pragma unroll
        for (int f = 0; f < 16; ++f)
            aft[f] = (x[f] - mean) * rs * W[LN1G + f] + W[LN1B + f];
    }
    // aft rows -> LDS, overlaying KbH[ag] (dead after P2; ordered by WB above)
    uint4* aftA = &KbH[ag][0][0];   // 64 uint4 per ag-group
    {
        u32 ac[8];
        #pragma unroll
        for (int c = 0; c < 8; ++c) ac[c] = h2u(pk2(aft[2*c], aft[2*c+1]));
        aftA[2*t]     = make_uint4(ac[0], ac[1], ac[2], ac[3]);
        aftA[2*t + 1] = make_uint4(ac[4], ac[5], ac[6], ac[7]);
    }
    WB();   // aft writes ordered before P4 reads

    // ---- P4: enc[t] = il_b[t] + aft_flat . il_w[:,t]  (f16 dot2) ----
    float enc = W[ILB + t];
    {
        const uint4* aA   = aftA;
        const uint4* ilw4 = (const uint4*)(Wu + ILWP);
        #pragma unroll 8
        for (int jp4 = 0; jp4 < 64; ++jp4) {
            uint4 av = aA[jp4];
            uint4 wv = ilw4[jp4 * 32 + t];
            enc = FD(u2h(av.x), u2h(wv.x), enc);
            enc = FD(u2h(av.y), u2h(wv.y), enc);
            enc = FD(u2h(av.z), u2h(wv.z), enc);
            enc = FD(u2h(av.w), u2h(wv.w), enc);
        }
    }
    WB();
    scr[t] = enc;   // overlays VbH[ag] (dead after P2; WB-fenced)
    WB();

    // ---- P5: GRU (h row re-read from global: uniform f4 broadcast, L1-warm) ----
    float gi0 = W[BIH + t], gi1 = W[BIH + 32 + t], gi2 = W[BIH + 64 + t];
    float gh0 = W[BHH + t], gh1 = W[BHH + 32 + t], gh2 = W[BHH + 64 + t];
    {
        const float4* eF = (const float4*)scr;
        const float4* hF = (const float4*)(hidden + (size_t)ba * 32);
        const uint4* wi4 = (const uint4*)(Wu + WIHP);
        const uint4* wh4 = (const uint4*)(Wu + WHHP);
        #pragma unroll
        for (int q4 = 0; q4 < 8; ++q4) {
            float4 ev = eF[q4], hv = hF[q4];
            h2 ea = pk2(ev.x, ev.y), eb = pk2(ev.z, ev.w);
            h2 ha = pk2(hv.x, hv.y), hb = pk2(hv.z, hv.w);
            uint4 wiA = wi4[(q4*2)*32 + t], wiB = wi4[(q4*2+1)*32 + t];
            uint4 whA = wh4[(q4*2)*32 + t], whB = wh4[(q4*2+1)*32 + t];
            gi0 = FD(ea, u2h(wiA.x), gi0); gi1 = FD(ea, u2h(wiA.y), gi1); gi2 = FD(ea, u2h(wiA.z), gi2);
            gi0 = FD(eb, u2h(wiB.x), gi0); gi1 = FD(eb, u2h(wiB.y), gi1); gi2 = FD(eb, u2h(wiB.z), gi2);
            gh0 = FD(ha, u2h(whA.x), gh0); gh1 = FD(ha, u2h(whA.y), gh1); gh2 = FD(ha, u2h(whA.z), gh2);
            gh0 = FD(hb, u2h(whB.x), gh0); gh1 = FD(hb, u2h(whB.y), gh1); gh2 = FD(hb, u2h(whB.z), gh2);
        }
    }
    float r  = sigm(gi0 + gh0);
    float z  = sigm(gi1 + gh1);
    float n  = tanhf(gi2 + r * gh2);
    float hn = (1.0f - z) * n + z * hp;
    outp[OUT_H + (size_t)ba * 32 + t] = hn;
    WB();
    scr[64 + t] = hn;
    WB();

    // ---- P6: memb = relu(h @ ms_w + b); msg = memb @ mg_w[a] + b ----
    {
        const float4* nF = (const float4*)(scr + 64);
        float mb = W[MSB + t];
        #pragma unroll
        for (int q4 = 0; q4 < 8; ++q4) {
            float4 v = nF[q4];
            h2 a2 = pk2(v.x, v.y), b2 = pk2(v.z, v.w);
            mb = FD(a2, u2h(Wu[MSWP + (q4*2)*32 + t]), mb);
            mb = FD(b2, u2h(Wu[MSWP + (q4*2+1)*32 + t]), mb);
        }
        mb = fmaxf(mb, 0.0f);
        WB();
        scr[96 + t] = mb;
        WB();
    }
    {
        const float4* mF = (const float4*)(scr + 96);
        float mg = W[MGB + a * 32 + t];
        #pragma unroll
        for (int q4 = 0; q4 < 8; ++q4) {
            float4 v = mF[q4];
            h2 a2 = pk2(v.x, v.y), b2 = pk2(v.z, v.w);
            mg = FD(a2, u2h(Wu[MGWP + a*512 + (q4*2)*32 + t]), mg);
            mg = FD(b2, u2h(Wu[MGWP + a*512 + (q4*2+1)*32 + t]), mg);
        }
        // stash raw per-agent message; k_mean overwrites with the mean
        outp[OUT_MM + (size_t)ba * 32 + t] = mg;
    }
}

// K2: per-batch message mean (in-place over OUT_MM) + degenerate comm-attn
// (sl=1 => softmax==1 => ao = (mm @ wkv_V + bkv_V) @ wo + bo, per batch).
// Both 32x32 matvecs 8-way parallelized across half-waves.
__global__ __launch_bounds__(256) void k_mean(const float* W, float* __restrict__ ao_ws,
                                              float* __restrict__ outp)
{
    const int b   = blockIdx.x;
    const int tid = threadIdx.x;
    const int t   = tid & 31;
    const int c   = tid >> 5;        // 0..7
    __shared__ float pS[8][32];
    __shared__ float mmS[32];
    __shared__ float vS[32];

    // mean over 64 agents (8-way partials)
    float acc = 0.0f;
    #pragma unroll
    for (int a2 = 0; a2 < 8; ++a2)
        acc += outp[OUT_MM + ((size_t)b * 64 + (a2 * 8 + c)) * 32 + t];
    pS[c][t] = acc;
    __syncthreads();
    if (tid < 32) {
        float ssum = 0.0f;
        #pragma unroll
        for (int cc = 0; cc < 8; ++cc) ssum += pS[cc][t];
        mmS[t] = ssum * (1.0f / 64.0f);
    }
    __syncthreads();
    // write mean_message output (broadcast to all 64 agents)
    {
        float mv = mmS[t];
        for (int i = tid; i < 2048; i += 256)
            outp[OUT_MM + (size_t)b * 2048 + i] = mv;   // i & 31 == t
    }
    // v = mm @ wkv_V + bkv_V  (each half-wave covers 4 k's)
    {
        float pv = 0.0f;
        #pragma unroll
        for (int kk = 0; kk < 4; ++kk) {
            int k = c * 4 + kk;
            pv += mmS[k] * W[MAWKVV + k * 32 + t];
        }
        pS[c][t] = pv;
    }
    __syncthreads();
    if (tid < 32) {
        float v = W[MABKVV + t];
        #pragma unroll
        for (int cc = 0; cc < 8; ++cc) v += pS[cc][t];
        vS[t] = v;
    }
    __syncthreads();
    // ao = v @ wo + bo
    {
        float po = 0.0f;
        #pragma unroll
        for (int kk = 0; kk < 4; ++kk) {
            int k = c * 4 + kk;
            po += vS[k] * W[MAWO + k * 32 + t];
        }
        pS[c][t] = po;
    }
    __syncthreads();
    if (tid < 32) {
        float o = W[MABO + t];
        #pragma unroll
        for (int cc = 0; cc < 8; ++cc) o += pS[cc][t];
        ao_ws[b * 32 + t] = o;
    }
}

// K3: LN2(h + ao[b]) -> feat=[h,after] -> relu(qs) -> per-agent Q head.
// 8192 blocks (one agent per half-wave slot) — all h loads issue in parallel.
// featS/qeS are half-wave-private ([ag]) -> WB() fences, no block barriers.
__global__ __launch_bounds__(256) void k_tail(
    const float* __restrict__ ao_ws, const float* W, float* __restrict__ outp)
{
    const u32* Wu = (const u32*)W;
    __shared__ __align__(16) float featS[8][64];
    __shared__ __align__(16) float qeS[8][32];
    const int w    = threadIdx.x >> 6;
    const int lane = threadIdx.x & 63;
    const int sub  = lane >> 5;
    const int t    = lane & 31;
    const int ag   = w * 2 + sub;
    const int pair = blockIdx.x * 4 + w;
    const int b    = pair >> 5;
    const int a    = ((pair & 31) << 1) | sub;
    const int ba   = b * 64 + a;

    float h  = outp[OUT_H + (size_t)ba * 32 + t];
    float ao = ao_ws[b * 32 + t];
    float x  = h + ao;
    float sm = x;
    #pragma unroll
    for (int m2 = 1; m2 < 32; m2 <<= 1) sm += __shfl_xor(sm, m2, 64);
    float mean = sm * (1.0f / 32.0f);
    float dx = x - mean;
    float vv = dx * dx;
    #pragma unroll
    for (int m2 = 1; m2 < 32; m2 <<= 1) vv += __shfl_xor(vv, m2, 64);
    float var   = vv * (1.0f / 32.0f);
    float after = dx * rsqrtf(var + 1e-5f) * W[LN2G + t] + W[LN2B + t];

    featS[ag][t]      = h;
    featS[ag][32 + t] = after;
    WB();   // half-wave-private: same-wave DS ordering, no block barrier
    {
        const float4* fF = (const float4*)&featS[ag][0];
        float acc = W[QSB + t];
        #pragma unroll
        for (int q4 = 0; q4 < 16; ++q4) {
            float4 v = fF[q4];
            h2 a2 = pk2(v.x, v.y), b2 = pk2(v.z, v.w);
            acc = FD(a2, u2h(Wu[QSWP + (q4*2)*32 + t]), acc);
            acc = FD(b2, u2h(Wu[QSWP + (q4*2+1)*32 + t]), acc);
        }
        acc = fmaxf(acc, 0.0f);
        WB();
        qeS[ag][t] = acc;
        WB();
    }
    if (t < 16) {
        const float4* qF = (const float4*)&qeS[ag][0];
        float qa = W[AHB + a * 16 + t];
        #pragma unroll
        for (int q4 = 0; q4 < 8; ++q4) {
            float4 v = qF[q4];
            h2 a2 = pk2(v.x, v.y), b2 = pk2(v.z, v.w);
            qa = FD(a2, u2h(Wu[AHWP + a*256 + (q4*2)*16 + t]), qa);
            qa = FD(b2, u2h(Wu[AHWP + a*256 + (q4*2+1)*16 + t]), qa);
        }
        outp[OUT_Q + (size_t)ba * 16 + t] = qa;
    }
}

extern "C" void kernel_launch(void* const* d_in, const int* in_sizes, int n_in,
                              void* d_out, int out_size, void* d_ws, size_t ws_size,
                              hipStream_t stream) {
    (void)in_sizes; (void)n_in; (void)out_size; (void)ws_size;
    WP wp;
    for (int i = 0; i < 30; ++i) wp.p[i] = (const float*)d_in[i + 2];

    float* W     = (float*)d_ws;
    float* ao_ws = W + W_ALLOC;   // 1024*32 f32

    const float* states = (const float*)d_in[0];
    const float* hidden = (const float*)d_in[1];
    float* outp = (float*)d_out;

    kw_conv<<<dim3((W_TOTAL + 255) / 256), dim3(256), 0, stream>>>(wp, W);
    k_main<<<dim3(8192), dim3(256), 0, stream>>>(states, hidden, W, outp);
    k_mean<<<dim3(1024), dim3(256), 0, stream>>>(W, ao_ws, outp);
    k_tail<<<dim3(8192), dim3(256), 0, stream>>>(ao_ws, W, outp);
}

// Round 5
// 445.968 us; speedup vs baseline: 1.0899x; 1.0008x over previous
//
#include <hip/hip_runtime.h>

typedef unsigned int u32;
typedef _Float16 f16;
typedef f16 h2 __attribute__((ext_vector_type(2)));

// ---------------- packed-weight ws layout (u32/f32 element offsets) ----------
#define QP     0        // [e<32][i<8] half2 pairs over f           (256)
#define KVP    256      // [e<64][i<8]                              (512)
#define WOP    768      // [f<16][i<16] pairs over e                (256)
#define ILWP   1024     // [(jp4<64 *32 + t)*4 + i] pairs over j    (8192)
#define WIHP   9216     // [(kp<16 *32 + t)*4 + j] j<3 used         (2048)
#define WHHP   11264    //                                          (2048)
#define MSWP   13312    // [kp<16 *32 + t]                          (512)
#define MGWP   13824    // [a*512 + kp<16 *32 + m]                  (32768)
#define QSWP   46592    // [kp<32 *32 + t]                          (1024)
#define AHWP   47616    // [a*256 + kp<16 *16 + u]                  (16384)
#define F32B   64000
#define BQ     (F32B+0)     // 32
#define BKV    (F32B+32)    // 64
#define BO     (F32B+96)    // 16
#define LN1G   (F32B+112)   // 16
#define LN1B   (F32B+128)   // 16
#define ILB    (F32B+144)   // 32
#define BIH    (F32B+176)   // 96
#define BHH    (F32B+272)   // 96
#define MSB    (F32B+368)   // 32
#define MGB    (F32B+400)   // 2048
#define MAWKVV (F32B+2448)  // 1024  wkv_V as [k<32][t<32]
#define MABKVV (F32B+3472)  // 32
#define MAWO   (F32B+3504)  // 1024
#define MABO   (F32B+4528)  // 32
#define LN2G   (F32B+4560)  // 32
#define LN2B   (F32B+4592)  // 32
#define QSB    (F32B+4624)  // 32
#define AHB    (F32B+4656)  // 1024
#define W_TOTAL (F32B+5680)
#define W_ALLOC 69696

// output element offsets (f32): q_values | h | mean_message
#define OUT_Q  0
#define OUT_H  1048576
#define OUT_MM 3145728

// softmax scale folded into wq/bq at repack time, in exp2 domain:
// CS = (1/sqrt(8)) * log2(e); score' = CS*(Q.K)  =>  exp(score*scale) = 2^score'
#define CS (0.35355339059327373f * 1.4426950408889634f)

// zero-cost compiler code-motion fence: guards type-punned LDS overlays
// (hardware same-wave DS ordering is already in-order; this only stops
// clang TBAA from reordering float vs uint4/float4 accesses to aliases)
#if __has_builtin(__builtin_amdgcn_wave_barrier)
#define WB() __builtin_amdgcn_wave_barrier()
#else
#define WB() __threadfence_block()
#endif

#if __has_builtin(__builtin_amdgcn_exp2f)
__device__ __forceinline__ float EXP2(float x) { return __builtin_amdgcn_exp2f(x); }
#else
__device__ __forceinline__ float EXP2(float x) { return __expf(x * 0.6931471805599453f); }
#endif

#if __has_builtin(__builtin_amdgcn_fdot2)
__device__ __forceinline__ float FD(h2 a, h2 b, float c) {
    return __builtin_amdgcn_fdot2(a, b, c, false);
}
#else
__device__ __forceinline__ float FD(h2 a, h2 b, float c) {
    return c + (float)a.x * (float)b.x + (float)a.y * (float)b.y;
}
#endif

#if __has_builtin(__builtin_amdgcn_cvt_pkrtz)
__device__ __forceinline__ h2 pk2(float a, float b) {
    auto r = __builtin_amdgcn_cvt_pkrtz(a, b);   // __fp16 vec2 on this clang
    h2 out;
    __builtin_memcpy(&out, &r, sizeof(out));      // no-op bitcast
    return out;
}
#else
__device__ __forceinline__ h2 pk2(float a, float b) { h2 r; r.x = (f16)a; r.y = (f16)b; return r; }
#endif

__device__ __forceinline__ h2  u2h(u32 x) { union { u32 u; h2 h; } c; c.u = x; return c.h; }
__device__ __forceinline__ u32 h2u(h2 x)  { union { u32 u; h2 h; } c; c.h = x; return c.u; }

__device__ __forceinline__ float sigm(float x) { return 1.0f / (1.0f + __expf(-x)); }

struct WP { const float* p[30]; };

// K0: repack weights: f16 pairs (packed along contraction dim) + f32 tail
__global__ void kw_conv(WP wp, float* W) {
    u32* Wu = (u32*)W;
    int gid = blockIdx.x * blockDim.x + threadIdx.x;
    if (gid >= W_TOTAL) return;
    if (gid < KVP) {                       // QP: ia_wq [16][32]  (x CS fold)
        int e = gid >> 3, i = gid & 7;
        const float* wq = wp.p[0];
        Wu[gid] = h2u(pk2(wq[(2*i)*32 + e] * CS, wq[(2*i+1)*32 + e] * CS));
    } else if (gid < WOP) {                // KVP: ia_wkv [16][64]
        int idx = gid - KVP; int e = idx >> 3, i = idx & 7;
        const float* wkv = wp.p[2];
        Wu[gid] = h2u(pk2(wkv[(2*i)*64 + e], wkv[(2*i+1)*64 + e]));
    } else if (gid < ILWP) {               // WOP: ia_wo [32][16]
        int idx = gid - WOP; int f = idx >> 4, i = idx & 15;
        const float* wo = wp.p[4];
        Wu[gid] = h2u(pk2(wo[(2*i)*16 + f], wo[(2*i+1)*16 + f]));
    } else if (gid < WIHP) {               // ILWP: il_w [512][32]
        int idx = gid - ILWP;
        int jp4 = idx >> 7, t = (idx >> 2) & 31, i = idx & 3;
        int jp = jp4 * 4 + i;
        const float* ilw = wp.p[8];
        Wu[gid] = h2u(pk2(ilw[(2*jp)*32 + t], ilw[(2*jp+1)*32 + t]));
    } else if (gid < WHHP) {               // WIHP: gru_wih [32][96]
        int idx = gid - WIHP;
        int kp = idx >> 7, t = (idx >> 2) & 31, j = idx & 3;
        const float* wih = wp.p[10];
        Wu[gid] = (j < 3) ? h2u(pk2(wih[(2*kp)*96 + j*32 + t], wih[(2*kp+1)*96 + j*32 + t])) : 0u;
    } else if (gid < MSWP) {               // WHHP: gru_whh [32][96]
        int idx = gid - WHHP;
        int kp = idx >> 7, t = (idx >> 2) & 31, j = idx & 3;
        const float* whh = wp.p[11];
        Wu[gid] = (j < 3) ? h2u(pk2(whh[(2*kp)*96 + j*32 + t], whh[(2*kp+1)*96 + j*32 + t])) : 0u;
    } else if (gid < MGWP) {               // MSWP: ms_w [32][32]
        int idx = gid - MSWP; int kp = idx >> 5, t = idx & 31;
        const float* msw = wp.p[14];
        Wu[gid] = h2u(pk2(msw[(2*kp)*32 + t], msw[(2*kp+1)*32 + t]));
    } else if (gid < QSWP) {               // MGWP: mg_w [64][32][32]
        int idx = gid - MGWP; int a = idx >> 9, rem = idx & 511, kp = rem >> 5, m = rem & 31;
        const float* mgw = wp.p[16];
        Wu[gid] = h2u(pk2(mgw[(a*32 + 2*kp)*32 + m], mgw[(a*32 + 2*kp+1)*32 + m]));
    } else if (gid < AHWP) {               // QSWP: qs_w [64][32]
        int idx = gid - QSWP; int kp = idx >> 5, t = idx & 31;
        const float* qsw = wp.p[26];
        Wu[gid] = h2u(pk2(qsw[(2*kp)*32 + t], qsw[(2*kp+1)*32 + t]));
    } else if (gid < F32B) {               // AHWP: ah_w [64][32][16]
        int idx = gid - AHWP; int a = idx >> 8, rem = idx & 255, kp = rem >> 4, u = rem & 15;
        const float* ahw = wp.p[28];
        Wu[gid] = h2u(pk2(ahw[(a*32 + 2*kp)*16 + u], ahw[(a*32 + 2*kp+1)*16 + u]));
    } else {                               // f32 tail
        int i = gid - F32B;
        float v;
        if      (i < 32)   v = wp.p[1][i] * CS;            // bq (x CS fold)
        else if (i < 96)   v = wp.p[3][i - 32];            // bkv
        else if (i < 112)  v = wp.p[5][i - 96];            // bo
        else if (i < 128)  v = wp.p[6][i - 112];           // ln1_g
        else if (i < 144)  v = wp.p[7][i - 128];           // ln1_b
        else if (i < 176)  v = wp.p[9][i - 144];           // il_b
        else if (i < 272)  v = wp.p[12][i - 176];          // gru_bih
        else if (i < 368)  v = wp.p[13][i - 272];          // gru_bhh
        else if (i < 400)  v = wp.p[15][i - 368];          // ms_b
        else if (i < 2448) v = wp.p[17][i - 400];          // mg_b
        else if (i < 3472) { int j = i - 2448; v = wp.p[20][(j >> 5)*64 + 32 + (j & 31)]; } // ma_wkv V
        else if (i < 3504) v = wp.p[21][32 + (i - 3472)];  // ma_bkv V
        else if (i < 4528) v = wp.p[22][i - 3504];         // ma_wo
        else if (i < 4560) v = wp.p[23][i - 4528];         // ma_bo
        else if (i < 4592) v = wp.p[24][i - 4560];         // ln2_g
        else if (i < 4624) v = wp.p[25][i - 4592];         // ln2_b
        else if (i < 4656) v = wp.p[27][i - 4624];         // qs_b
        else               v = wp.p[29][i - 4656];         // ah_b
        W[gid] = v;
    }
}

// K1: per wave = 2 agents. lane = (sub<<5)|t ; t = link/row index.
// ALL LDS regions are wave-private ([ag] with ag owned by the wave), so no
// __syncthreads is needed anywhere: same-wave DS ops execute in order at the
// hardware level; WB() (zero-instruction wave_barrier) pins the compiler's
// memory-op order at every type-punned overlay transition.
// LDS exactly 32 KiB. Scratch (enc/hn/memb) overlays VbH[ag] (dead after P2);
// h is re-read from global (L1-warm).
// launch_bounds (256,5): MEASURED best — r2/r4 (,5): 48 VGPR, zero scratch,
// WRITE=16MB, 264-265us. r0/r3 (,4): 64 VGPR + ~130B/thread scratch spill
// (WRITE 229-295MB, FETCH +90MB), 291-299us. Do not relax to (,4).
__global__ __launch_bounds__(256, 5) void k_main(
    const float* __restrict__ states, const float* __restrict__ hidden,
    const float* W, float* __restrict__ outp)
{
    const u32* Wu = (const u32*)W;

    __shared__ uint4 KbH[8][32][4];   // f16 K rows (swizzled); later: aft rows
    __shared__ uint4 VbH[8][32][4];   // f16 V rows (swizzled); later: scratch

    const int w    = threadIdx.x >> 6;
    const int lane = threadIdx.x & 63;
    const int sub  = lane >> 5;
    const int t    = lane & 31;
    const int ag   = w * 2 + sub;
    const int pair = blockIdx.x * 4 + w;
    const int b    = pair >> 5;
    const int a    = ((pair & 31) << 1) | sub;
    const int ba   = b * 64 + a;

    float* scr = (float*)&VbH[ag][0][0];   // 512 f32; [0..31]=enc [64..95]=hn [96..127]=memb

    // ---- P0: states row (link t): 16 f32; hidden value (latency overlap) ----
    float s[16];
    {
        const float4* p4 = reinterpret_cast<const float4*>(states + ((size_t)ba * 32 + t) * 16);
        float4 f0 = p4[0], f1 = p4[1], f2 = p4[2], f3 = p4[3];
        s[0]=f0.x; s[1]=f0.y; s[2]=f0.z; s[3]=f0.w;
        s[4]=f1.x; s[5]=f1.y; s[6]=f1.z; s[7]=f1.w;
        s[8]=f2.x; s[9]=f2.y; s[10]=f2.z; s[11]=f2.w;
        s[12]=f3.x; s[13]=f3.y; s[14]=f3.z; s[15]=f3.w;
    }
    float hp = hidden[(size_t)ba * 32 + t];
    h2 sh[8];
    #pragma unroll
    for (int i = 0; i < 8; ++i) sh[i] = pk2(s[2*i], s[2*i+1]);

    // ---- P1a: Q (packed pairs; weights wave-uniform -> s_load). wq/bq carry
    //           the CS = scale*log2e fold, so scores land in exp2 domain. ----
    h2 qh[16];
    #pragma unroll
    for (int j = 0; j < 16; ++j) {
        float a0 = W[BQ + 2*j], a1 = W[BQ + 2*j + 1];
        #pragma unroll
        for (int i = 0; i < 8; ++i) {
            a0 = FD(sh[i], u2h(Wu[QP + (2*j)*8 + i]), a0);
            a1 = FD(sh[i], u2h(Wu[QP + (2*j+1)*8 + i]), a1);
        }
        qh[j] = pk2(a0, a1);
    }
    // ---- P1b: K,V rows -> f16 LDS (swizzled cols) ----
    #pragma unroll
    for (int u = 0; u < 4; ++u) {
        u32 kc[4], vc[4];
        #pragma unroll
        for (int c = 0; c < 4; ++c) {
            int e0 = u*8 + 2*c, e1 = e0 + 1;
            float k0 = W[BKV+e0], k1 = W[BKV+e1];
            float v0 = W[BKV+32+e0], v1 = W[BKV+32+e1];
            #pragma unroll
            for (int i = 0; i < 8; ++i) {
                k0 = FD(sh[i], u2h(Wu[KVP + e0*8 + i]), k0);
                k1 = FD(sh[i], u2h(Wu[KVP + e1*8 + i]), k1);
                v0 = FD(sh[i], u2h(Wu[KVP + (32+e0)*8 + i]), v0);
                v1 = FD(sh[i], u2h(Wu[KVP + (32+e1)*8 + i]), v1);
            }
            kc[c] = h2u(pk2(k0, k1)); vc[c] = h2u(pk2(v0, v1));
        }
        int uc = u ^ (t & 3);
        KbH[ag][t][uc] = make_uint4(kc[0], kc[1], kc[2], kc[3]);
        VbH[ag][t][uc] = make_uint4(vc[0], vc[1], vc[2], vc[3]);
    }
    WB();   // K/V writes ordered before P2 reads (same wave, in-order DS pipe)

    // ---- P2: 4-head attention; fused score+PV loop (no scf array);
    //          e = exp2(sc) (scale pre-folded); PV in packed f16 ----
    h2 oh[16];
    #pragma unroll
    for (int hh = 0; hh < 4; ++hh) {
        float l = 0.0f;
        h2 ov0 = {(f16)0, (f16)0}, ov1 = ov0, ov2 = ov0, ov3 = ov0;
        #pragma unroll
        for (int k = 0; k < 32; ++k) {
            uint4 kr = KbH[ag][k][hh ^ (k & 3)];   // uniform addr -> broadcast
            float sc = 0.0f;
            sc = FD(qh[hh*4+0], u2h(kr.x), sc);
            sc = FD(qh[hh*4+1], u2h(kr.y), sc);
            sc = FD(qh[hh*4+2], u2h(kr.z), sc);
            sc = FD(qh[hh*4+3], u2h(kr.w), sc);
            float e = EXP2(sc);
            l += e;
            h2 ph = pk2(e, e);
            uint4 vr = VbH[ag][k][hh ^ (k & 3)];
            ov0 += ph * u2h(vr.x);
            ov1 += ph * u2h(vr.y);
            ov2 += ph * u2h(vr.z);
            ov3 += ph * u2h(vr.w);
        }
        float inv = 1.0f / l;
        h2 hinv = pk2(inv, inv);
        oh[hh*4+0] = ov0 * hinv; oh[hh*4+1] = ov1 * hinv;
        oh[hh*4+2] = ov2 * hinv; oh[hh*4+3] = ov3 * hinv;
    }
    WB();   // all KbH/VbH reads complete-in-order before overlay writes below

    // ---- P3: out proj + residual + LayerNorm(16) ----
    float aft[16];
    {
        float x[16];
        float mean = 0.0f;
        #pragma unroll
        for (int f = 0; f < 16; ++f) {
            float acc = W[BO + f];
            #pragma unroll
            for (int i = 0; i < 16; ++i) acc = FD(oh[i], u2h(Wu[WOP + f*16 + i]), acc);
            x[f] = s[f] + acc;
            mean += x[f];
        }
        mean *= (1.0f / 16.0f);
        float var = 0.0f;
        #pragma unroll
        for (int f = 0; f < 16; ++f) { float d = x[f] - mean; var += d * d; }
        var *= (1.0f / 16.0f);
        float rs = rsqrtf(var + 1e-5f);
        #pragma unroll
        for (int f = 0; f < 16; ++f)
            aft[f] = (x[f] - mean) * rs * W[LN1G + f] + W[LN1B + f];
    }
    // aft rows -> LDS, overlaying KbH[ag] (dead after P2; ordered by WB above)
    uint4* aftA = &KbH[ag][0][0];   // 64 uint4 per ag-group
    {
        u32 ac[8];
        #pragma unroll
        for (int c = 0; c < 8; ++c) ac[c] = h2u(pk2(aft[2*c], aft[2*c+1]));
        aftA[2*t]     = make_uint4(ac[0], ac[1], ac[2], ac[3]);
        aftA[2*t + 1] = make_uint4(ac[4], ac[5], ac[6], ac[7]);
    }
    WB();   // aft writes ordered before P4 reads

    // ---- P4: enc[t] = il_b[t] + aft_flat . il_w[:,t]  (f16 dot2) ----
    float enc = W[ILB + t];
    {
        const uint4* aA   = aftA;
        const uint4* ilw4 = (const uint4*)(Wu + ILWP);
        #pragma unroll 8
        for (int jp4 = 0; jp4 < 64; ++jp4) {
            uint4 av = aA[jp4];
            uint4 wv = ilw4[jp4 * 32 + t];
            enc = FD(u2h(av.x), u2h(wv.x), enc);
            enc = FD(u2h(av.y), u2h(wv.y), enc);
            enc = FD(u2h(av.z), u2h(wv.z), enc);
            enc = FD(u2h(av.w), u2h(wv.w), enc);
        }
    }
    WB();
    scr[t] = enc;   // overlays VbH[ag] (dead after P2; WB-fenced)
    WB();

    // ---- P5: GRU (h row re-read from global: uniform f4 broadcast, L1-warm) ----
    float gi0 = W[BIH + t], gi1 = W[BIH + 32 + t], gi2 = W[BIH + 64 + t];
    float gh0 = W[BHH + t], gh1 = W[BHH + 32 + t], gh2 = W[BHH + 64 + t];
    {
        const float4* eF = (const float4*)scr;
        const float4* hF = (const float4*)(hidden + (size_t)ba * 32);
        const uint4* wi4 = (const uint4*)(Wu + WIHP);
        const uint4* wh4 = (const uint4*)(Wu + WHHP);
        #pragma unroll
        for (int q4 = 0; q4 < 8; ++q4) {
            float4 ev = eF[q4], hv = hF[q4];
            h2 ea = pk2(ev.x, ev.y), eb = pk2(ev.z, ev.w);
            h2 ha = pk2(hv.x, hv.y), hb = pk2(hv.z, hv.w);
            uint4 wiA = wi4[(q4*2)*32 + t], wiB = wi4[(q4*2+1)*32 + t];
            uint4 whA = wh4[(q4*2)*32 + t], whB = wh4[(q4*2+1)*32 + t];
            gi0 = FD(ea, u2h(wiA.x), gi0); gi1 = FD(ea, u2h(wiA.y), gi1); gi2 = FD(ea, u2h(wiA.z), gi2);
            gi0 = FD(eb, u2h(wiB.x), gi0); gi1 = FD(eb, u2h(wiB.y), gi1); gi2 = FD(eb, u2h(wiB.z), gi2);
            gh0 = FD(ha, u2h(whA.x), gh0); gh1 = FD(ha, u2h(whA.y), gh1); gh2 = FD(ha, u2h(whA.z), gh2);
            gh0 = FD(hb, u2h(whB.x), gh0); gh1 = FD(hb, u2h(whB.y), gh1); gh2 = FD(hb, u2h(whB.z), gh2);
        }
    }
    float r  = sigm(gi0 + gh0);
    float z  = sigm(gi1 + gh1);
    float n  = tanhf(gi2 + r * gh2);
    float hn = (1.0f - z) * n + z * hp;
    outp[OUT_H + (size_t)ba * 32 + t] = hn;
    WB();
    scr[64 + t] = hn;
    WB();

    // ---- P6: memb = relu(h @ ms_w + b); msg = memb @ mg_w[a] + b ----
    {
        const float4* nF = (const float4*)(scr + 64);
        float mb = W[MSB + t];
        #pragma unroll
        for (int q4 = 0; q4 < 8; ++q4) {
            float4 v = nF[q4];
            h2 a2 = pk2(v.x, v.y), b2 = pk2(v.z, v.w);
            mb = FD(a2, u2h(Wu[MSWP + (q4*2)*32 + t]), mb);
            mb = FD(b2, u2h(Wu[MSWP + (q4*2+1)*32 + t]), mb);
        }
        mb = fmaxf(mb, 0.0f);
        WB();
        scr[96 + t] = mb;
        WB();
    }
    {
        const float4* mF = (const float4*)(scr + 96);
        float mg = W[MGB + a * 32 + t];
        #pragma unroll
        for (int q4 = 0; q4 < 8; ++q4) {
            float4 v = mF[q4];
            h2 a2 = pk2(v.x, v.y), b2 = pk2(v.z, v.w);
            mg = FD(a2, u2h(Wu[MGWP + a*512 + (q4*2)*32 + t]), mg);
            mg = FD(b2, u2h(Wu[MGWP + a*512 + (q4*2+1)*32 + t]), mg);
        }
        // stash raw per-agent message; k_mean overwrites with the mean
        outp[OUT_MM + (size_t)ba * 32 + t] = mg;
    }
}

// K2: per-batch message mean (in-place over OUT_MM) + degenerate comm-attn
// (sl=1 => softmax==1 => ao = (mm @ wkv_V + bkv_V) @ wo + bo, per batch).
// 512 threads: 16-way partials (4 loads/thread); the two 32x32 matvecs run
// in half-wave 0 with a 32-step __shfl dot (no vS LDS, 3 fewer barriers).
__global__ __launch_bounds__(512) void k_mean(const float* W, float* __restrict__ ao_ws,
                                              float* __restrict__ outp)
{
    const int b   = blockIdx.x;
    const int tid = threadIdx.x;
    const int t   = tid & 31;
    const int c   = tid >> 5;        // 0..15
    __shared__ float pS[16][32];
    __shared__ float mmS[32];

    // mean over 64 agents (16-way partials, 4 loads each)
    float acc = 0.0f;
    #pragma unroll
    for (int a2 = 0; a2 < 4; ++a2)
        acc += outp[OUT_MM + ((size_t)b * 64 + (a2 * 16 + c)) * 32 + t];
    pS[c][t] = acc;
    __syncthreads();
    if (tid < 32) {
        float ssum = 0.0f;
        #pragma unroll
        for (int cc = 0; cc < 16; ++cc) ssum += pS[cc][t];
        mmS[t] = ssum * (1.0f / 64.0f);
    }
    __syncthreads();
    // write mean_message output (broadcast to all 64 agents): 4 stores/thread
    {
        float mv = mmS[t];
        #pragma unroll
        for (int i = 0; i < 4; ++i)
            outp[OUT_MM + (size_t)b * 2048 + i * 512 + tid] = mv;  // (i*512+tid)&31==t
    }
    // ao chain entirely in half-wave 0: v = mm@wkv_V + bkv_V; ao = v@wo + bo.
    // cross-lane v[k] via __shfl (lanes 0..31 all active; k<32).
    if (tid < 32) {
        float v = W[MABKVV + t];
        #pragma unroll 8
        for (int k = 0; k < 32; ++k) v += mmS[k] * W[MAWKVV + k * 32 + t];
        float o = W[MABO + t];
        #pragma unroll 8
        for (int k = 0; k < 32; ++k) o += __shfl(v, k, 64) * W[MAWO + k * 32 + t];
        ao_ws[b * 32 + t] = o;
    }
}

// K3: LN2(h + ao[b]) -> feat=[h,after] -> relu(qs) -> per-agent Q head.
// 4096 blocks x 512 threads (same wave count as 8192x256, half the dispatch
// packets). featS/qeS are half-wave-private ([ag]) -> WB() fences only.
__global__ __launch_bounds__(512) void k_tail(
    const float* __restrict__ ao_ws, const float* W, float* __restrict__ outp)
{
    const u32* Wu = (const u32*)W;
    __shared__ __align__(16) float featS[16][64];
    __shared__ __align__(16) float qeS[16][32];
    const int w    = threadIdx.x >> 6;        // 0..7
    const int lane = threadIdx.x & 63;
    const int sub  = lane >> 5;
    const int t    = lane & 31;
    const int ag   = w * 2 + sub;             // 0..15
    const int pair = blockIdx.x * 8 + w;
    const int b    = pair >> 5;
    const int a    = ((pair & 31) << 1) | sub;
    const int ba   = b * 64 + a;

    float h  = outp[OUT_H + (size_t)ba * 32 + t];
    float ao = ao_ws[b * 32 + t];
    float x  = h + ao;
    float sm = x;
    #pragma unroll
    for (int m2 = 1; m2 < 32; m2 <<= 1) sm += __shfl_xor(sm, m2, 64);
    float mean = sm * (1.0f / 32.0f);
    float dx = x - mean;
    float vv = dx * dx;
    #pragma unroll
    for (int m2 = 1; m2 < 32; m2 <<= 1) vv += __shfl_xor(vv, m2, 64);
    float var   = vv * (1.0f / 32.0f);
    float after = dx * rsqrtf(var + 1e-5f) * W[LN2G + t] + W[LN2B + t];

    featS[ag][t]      = h;
    featS[ag][32 + t] = after;
    WB();   // half-wave-private: same-wave DS ordering, no block barrier
    {
        const float4* fF = (const float4*)&featS[ag][0];
        float acc = W[QSB + t];
        #pragma unroll
        for (int q4 = 0; q4 < 16; ++q4) {
            float4 v = fF[q4];
            h2 a2 = pk2(v.x, v.y), b2 = pk2(v.z, v.w);
            acc = FD(a2, u2h(Wu[QSWP + (q4*2)*32 + t]), acc);
            acc = FD(b2, u2h(Wu[QSWP + (q4*2+1)*32 + t]), acc);
        }
        acc = fmaxf(acc, 0.0f);
        WB();
        qeS[ag][t] = acc;
        WB();
    }
    if (t < 16) {
        const float4* qF = (const float4*)&qeS[ag][0];
        float qa = W[AHB + a * 16 + t];
        #pragma unroll
        for (int q4 = 0; q4 < 8; ++q4) {
            float4 v = qF[q4];
            h2 a2 = pk2(v.x, v.y), b2 = pk2(v.z, v.w);
            qa = FD(a2, u2h(Wu[AHWP + a*256 + (q4*2)*16 + t]), qa);
            qa = FD(b2, u2h(Wu[AHWP + a*256 + (q4*2+1)*16 + t]), qa);
        }
        outp[OUT_Q + (size_t)ba * 16 + t] = qa;
    }
}

extern "C" void kernel_launch(void* const* d_in, const int* in_sizes, int n_in,
                              void* d_out, int out_size, void* d_ws, size_t ws_size,
                              hipStream_t stream) {
    (void)in_sizes; (void)n_in; (void)out_size; (void)ws_size;
    WP wp;
    for (int i = 0; i < 30; ++i) wp.p[i] = (const float*)d_in[i + 2];

    float* W     = (float*)d_ws;
    float* ao_ws = W + W_ALLOC;   // 1024*32 f32

    const float* states = (const float*)d_in[0];
    const float* hidden = (const float*)d_in[1];
    float* outp = (float*)d_out;

    kw_conv<<<dim3((W_TOTAL + 255) / 256), dim3(256), 0, stream>>>(wp, W);
    k_main<<<dim3(8192), dim3(256), 0, stream>>>(states, hidden, W, outp);
    k_mean<<<dim3(1024), dim3(512), 0, stream>>>(W, ao_ws, outp);
    k_tail<<<dim3(4096), dim3(512), 0, stream>>>(ao_ws, W, outp);
}